// Round 5
// baseline (520.268 us; speedup 1.0000x reference)
//
#include <hip/hip_runtime.h>
#include <math.h>

#define C_IN   64
#define T_DIM  256
#define V_DIM  25
#define C_OUT  256
#define S_DIM  3
#define BN_EPS 1e-5f

#define SC       (S_DIM * C_IN)          // 192
#define TW       (T_DIM * V_DIM)         // 6400
#define AP_PER_N (S_DIM * V_DIM * V_DIM) // 1875
#define LDB      200                     // sXa row stride in bf16 (400 B)
#define LDX      32                      // sX row stride in bf16 (64 B)
#define NR       32                      // atomic replica count
#define NITER    16                      // t-pairs per block

typedef __attribute__((ext_vector_type(8))) short bf16x8;
typedef __attribute__((ext_vector_type(4))) float f32x4;

__device__ __forceinline__ unsigned short f2bf(float f) {
    unsigned u = __builtin_bit_cast(unsigned, f);
    unsigned r = u + 0x7fffu + ((u >> 16) & 1u);
    return (unsigned short)(r >> 16);
}

// ---------------------------------------------------------------------------
// A_personalized = tanh(A_pers[:n]) -> output 0
// ---------------------------------------------------------------------------
__global__ void k_prep_a(const float* __restrict__ A_pers, float* __restrict__ out_ap,
                         int total) {
    int i = blockIdx.x * 256 + threadIdx.x;
    if (i < total) out_ap[i] = tanhf(A_pers[i]);
}

// ---------------------------------------------------------------------------
// Pack A_final = A + tanh(A_pers) into exact MFMA B-fragment layout (bf16):
// afb[n][s][nt][lane][i] = Af[v = (lane>>4)*8+i][w = nt*16 + (lane&15)], 0-pad
// ---------------------------------------------------------------------------
__global__ void k_prep_afb(const float* __restrict__ A, const float* __restrict__ A_pers,
                           unsigned short* __restrict__ afb, int total) {
    int j = blockIdx.x * 256 + threadIdx.x;
    if (j >= total) return;
    int i    = j & 7;
    int lane = (j >> 3) & 63;
    int nt   = (j >> 9) & 1;
    int sn   = j >> 10;          // n*3 + s
    int s    = sn % 3;
    int n    = sn / 3;
    int v    = ((lane >> 4) << 3) + i;
    int w    = nt * 16 + (lane & 15);
    float val = 0.f;
    if (v < V_DIM && w < V_DIM)
        val = A[(s * V_DIM + v) * V_DIM + w] +
              tanhf(A_pers[((n * S_DIM + s) * V_DIM + v) * V_DIM + w]);
    afb[j] = f2bf(val);
}

// ---------------------------------------------------------------------------
// conv_w (S,C_OUT,C_IN) -> bf16 wt_b[o][sc], sc = s*64+c (stage-2 A-frag rows)
// ---------------------------------------------------------------------------
__global__ void k_prep_w(const float* __restrict__ conv_w, unsigned short* __restrict__ wt_b) {
    int j = blockIdx.x * 256 + threadIdx.x;    // C_OUT*SC = 49152
    if (j < C_OUT * SC) {
        int o  = j / SC;
        int sc = j - o * SC;
        int s  = sc >> 6, c = sc & 63;
        wt_b[j] = f2bf(conv_w[(s * C_OUT + o) * C_IN + c]);
    }
}

// ---------------------------------------------------------------------------
// Main: persistent block = (n fixed, 16 consecutive t-pairs). Weights + afb
// register-resident; x prefetch double-buffered in registers.
// PASS 0: channel sums (LDS bins -> one global atomic/thread). PASS 1: BN+ReLU y.
// ---------------------------------------------------------------------------
template <int PASS>
__global__ __launch_bounds__(256, 2) void k_main(const float* __restrict__ x,
                                                 const unsigned short* __restrict__ afb,
                                                 const unsigned short* __restrict__ wt_b,
                                                 float* __restrict__ y,
                                                 float* __restrict__ bins,
                                                 const float2* __restrict__ ssv) {
    __shared__ __align__(16) unsigned short sX[128 * LDX];   // 8 KB    [ct=2c+t][v pad 32]
    __shared__ __align__(16) unsigned short sXa[64 * LDB];   // 25.6 KB [tw][sc pad 200]
    __shared__ float  sSum[C_OUT];
    __shared__ float  sSqs[C_OUT];
    __shared__ float2 sSS[C_OUT];

    const int tid    = threadIdx.x;
    const int bid    = blockIdx.x;
    const int nIdx   = bid >> 3;           // 8 blocks per n
    const int tpBase = (bid & 7) * NITER;  // first t-pair
    const int lane   = tid & 63;
    const int wv     = tid >> 6;
    const int l15    = lane & 15;
    const int kg     = lane >> 4;

    // ---- register-resident weights: 24 x b128 (96 VGPR) ----
    bf16x8 aF[4][6];
    {
        const unsigned short* wrow = wt_b + (size_t)(wv * 64 + l15) * SC + kg * 8;
#pragma unroll
        for (int m = 0; m < 4; ++m)
#pragma unroll
            for (int ks = 0; ks < 6; ++ks)
                aF[m][ks] = *(const bf16x8*)(wrow + m * 16 * SC + ks * 32);
    }
    // ---- register-resident stage-1 B-frags (afb): 6 x b128 ----
    bf16x8 bS[6];
    {
        const unsigned short* afbN = afb + (size_t)nIdx * (6 * 64 * 8);
#pragma unroll
        for (int sq = 0; sq < 6; ++sq)
            bS[sq] = *(const bf16x8*)(afbN + (sq * 64 + lane) * 8);
    }

    // zero K-pad cols v=25..31 of sX (never overwritten)
    for (int j = tid; j < 128 * 4; j += 256) {
        int row = j >> 2, p = j & 3;
        if (p == 0) sX[row * LDX + 25] = 0;
        else ((unsigned*)sX)[row * (LDX / 2) + 12 + p] = 0;
    }
    if (PASS == 0) { sSum[tid] = 0.f; sSqs[tid] = 0.f; }
    else           { sSS[tid] = ssv[tid]; }

    // ---- prefetch x tile 0 into registers ----
    const float* xb0 = x + (size_t)nIdx * C_IN * TW + (size_t)tpBase * 2 * V_DIM;
    float2 xp[7];
#pragma unroll
    for (int k = 0; k < 7; ++k) {
        int q  = tid + k * 256;
        int qq = q < 1600 ? q : 0;
        int c  = qq / 25, j = qq - c * 25;
        xp[k] = *(const float2*)(xb0 + (size_t)c * TW + 2 * j);
    }

#pragma unroll 1
    for (int it = 0; it < NITER; ++it) {
        // ---- write prefetched x -> sX (bf16) ----
#pragma unroll
        for (int k = 0; k < 7; ++k) {
            int q = tid + k * 256;
            if (q < 1600) {
                int c = q / 25, j = q - c * 25;
                unsigned short b0 = f2bf(xp[k].x), b1 = f2bf(xp[k].y);
                if (j < 12) {
                    ((unsigned*)sX)[c * LDX + j] = (unsigned)b0 | ((unsigned)b1 << 16);
                } else if (j == 12) {
                    sX[(2 * c) * LDX + 24] = b0;
                    sX[(2 * c + 1) * LDX]  = b1;
                } else {
                    int v = 2 * j - 25;
                    sX[(2 * c + 1) * LDX + v]     = b0;
                    sX[(2 * c + 1) * LDX + v + 1] = b1;
                }
            }
        }
        // ---- issue next-tile prefetch (no wait) ----
        if (it + 1 < NITER) {
            const float* xbn = xb0 + (size_t)(it + 1) * 2 * V_DIM;
#pragma unroll
            for (int k = 0; k < 7; ++k) {
                int q  = tid + k * 256;
                int qq = q < 1600 ? q : 0;
                int c  = qq / 25, j = qq - c * 25;
                xp[k] = *(const float2*)(xbn + (size_t)c * TW + 2 * j);
            }
        }
        __syncthreads();   // A: sX ready; sXa free (prev stage-2 reads done)

        // ---- stage 1: 12 MFMA/wave; paired-bf16 b32 LDS writes ----
#pragma unroll
        for (int sq = 0; sq < 6; ++sq) {
            int s = sq >> 1, nt = sq & 1;
            int w = nt * 16 + l15;
#pragma unroll
            for (int m2 = 0; m2 < 2; ++m2) {
                int mt = wv * 2 + m2;
                bf16x8 aX = *(const bf16x8*)(sX + (mt * 16 + l15) * LDX + kg * 8);
                f32x4 c4 = __builtin_amdgcn_mfma_f32_16x16x32_bf16(
                    aX, bS[sq], (f32x4){0.f, 0.f, 0.f, 0.f}, 0, 0, 0);
                if (w < V_DIM) {
                    unsigned u0 = (unsigned)f2bf(c4[0]) | ((unsigned)f2bf(c4[2]) << 16); // t=0
                    unsigned u1 = (unsigned)f2bf(c4[1]) | ((unsigned)f2bf(c4[3]) << 16); // t=1
                    unsigned col = s * 32 + mt * 4 + kg;
                    ((unsigned*)sXa)[w * (LDB / 2) + col]           = u0;
                    ((unsigned*)sXa)[(V_DIM + w) * (LDB / 2) + col] = u1;
                }
            }
        }
        __syncthreads();   // B: sXa ready; sX free for next write

        // ---- stage 2: M=256 (o), N=64 (tw, 50 valid), K=192; aF in registers ----
        f32x4 acc[4][4];
#pragma unroll
        for (int m = 0; m < 4; ++m)
#pragma unroll
            for (int nn = 0; nn < 4; ++nn) acc[m][nn] = (f32x4){0.f, 0.f, 0.f, 0.f};
#pragma unroll
        for (int ks = 0; ks < 6; ++ks) {
            bf16x8 bF[4];
#pragma unroll
            for (int nn = 0; nn < 4; ++nn)
                bF[nn] = *(const bf16x8*)(sXa + (nn * 16 + l15) * LDB + ks * 32 + kg * 8);
#pragma unroll
            for (int m = 0; m < 4; ++m)
#pragma unroll
                for (int nn = 0; nn < 4; ++nn)
                    acc[m][nn] = __builtin_amdgcn_mfma_f32_16x16x32_bf16(aF[m][ks], bF[nn], acc[m][nn], 0, 0, 0);
        }

        const int wbase = wv * 64;
        if (PASS == 0) {
#pragma unroll
            for (int m = 0; m < 4; ++m) {
#pragma unroll
                for (int r = 0; r < 4; ++r) {
                    float s1, s2;
                    {
                        float v0 = acc[m][0][r], v1 = acc[m][1][r], v2 = acc[m][2][r];
                        s1 = v0 + v1 + v2;
                        s2 = v0 * v0 + v1 * v1 + v2 * v2;
                        if (l15 < 2) {           // tw = 48+l15 < 50
                            float v3 = acc[m][3][r];
                            s1 += v3;
                            s2 += v3 * v3;
                        }
                    }
#pragma unroll
                    for (int off = 1; off < 16; off <<= 1) {
                        s1 += __shfl_xor(s1, off, 64);
                        s2 += __shfl_xor(s2, off, 64);
                    }
                    if (l15 == 0) {
                        int o = wbase + m * 16 + kg * 4 + r;
                        atomicAdd(&sSum[o], s1);
                        atomicAdd(&sSqs[o], s2);
                    }
                }
            }
        } else {
            const size_t ybase = (size_t)nIdx * C_OUT * TW + (size_t)(tpBase + it) * 2 * V_DIM;
#pragma unroll
            for (int m = 0; m < 4; ++m) {
#pragma unroll
                for (int r = 0; r < 4; ++r) {
                    int o = wbase + m * 16 + kg * 4 + r;
                    float2 sh = sSS[o];
                    float* yp = y + ybase + (size_t)o * TW + l15;
                    yp[0]  = fmaxf(fmaf(acc[m][0][r], sh.x, sh.y), 0.f);
                    yp[16] = fmaxf(fmaf(acc[m][1][r], sh.x, sh.y), 0.f);
                    yp[32] = fmaxf(fmaf(acc[m][2][r], sh.x, sh.y), 0.f);
                    if (l15 < 2)
                        yp[48] = fmaxf(fmaf(acc[m][3][r], sh.x, sh.y), 0.f);
                }
            }
        }
    }

    if (PASS == 0) {
        __syncthreads();
        const int rep = bid & (NR - 1);
        atomicAdd(&bins[rep * 2 * C_OUT + tid], sSum[tid]);
        atomicAdd(&bins[rep * 2 * C_OUT + C_OUT + tid], sSqs[tid]);
    }
}

// ---------------------------------------------------------------------------
// Reduce replica bins -> per-channel scale/shift
// ---------------------------------------------------------------------------
__global__ void k_stats(const float* __restrict__ bins, const float* __restrict__ bn_w,
                        const float* __restrict__ bn_b, float2* __restrict__ ssv, int n) {
    int o = threadIdx.x;   // 256
    float s1 = 0.f, s2 = 0.f;
    for (int rp = 0; rp < NR; ++rp) {
        s1 += bins[rp * 2 * C_OUT + o];
        s2 += bins[rp * 2 * C_OUT + C_OUT + o];
    }
    float cnt   = (float)n * (float)TW;
    float mean  = s1 / cnt;
    float var   = s2 / cnt - mean * mean;
    float scale = bn_w[o] * rsqrtf(var + BN_EPS);
    ssv[o] = make_float2(scale, bn_b[o] - mean * scale);
}

// ---------------------------------------------------------------------------
extern "C" void kernel_launch(void* const* d_in, const int* in_sizes, int n_in,
                              void* d_out, int out_size, void* d_ws, size_t ws_size,
                              hipStream_t stream) {
    const float* x      = (const float*)d_in[0];
    const float* A      = (const float*)d_in[1];
    const float* A_pers = (const float*)d_in[2];
    const float* conv_w = (const float*)d_in[3];
    // d_in[4] = conv_b: cancels under training-mode BatchNorm -> unused
    const float* bn_w   = (const float*)d_in[5];
    const float* bn_b   = (const float*)d_in[6];

    const int n = in_sizes[0] / (C_IN * TW);   // 64

    float* out_ap = (float*)d_out;
    float* y      = (float*)d_out + (size_t)n * AP_PER_N;

    // ws layout (16B aligned blocks)
    float*  bins = (float*)d_ws;                                   // NR*2*C_OUT floats (64 KB)
    float2* ssv  = (float2*)(bins + NR * 2 * C_OUT);               // C_OUT float2 (2 KB)
    unsigned short* afb  = (unsigned short*)((char*)(ssv + C_OUT));// n*6*64*8 bf16 (384 KB)
    unsigned short* wt_b = afb + (size_t)n * 6 * 64 * 8;           // C_OUT*SC bf16 (96 KB)

    hipMemsetAsync(bins, 0, NR * 2 * C_OUT * sizeof(float), stream);

    int totA = n * AP_PER_N;
    k_prep_a<<<(totA + 255) / 256, 256, 0, stream>>>(A_pers, out_ap, totA);
    int totF = n * 6 * 64 * 8;
    k_prep_afb<<<(totF + 255) / 256, 256, 0, stream>>>(A, A_pers, afb, totF);
    k_prep_w<<<(C_OUT * SC + 255) / 256, 256, 0, stream>>>(conv_w, wt_b);

    dim3 grid(n * 8);   // 512 persistent blocks, 16 t-pairs each
    k_main<0><<<grid, 256, 0, stream>>>(x, afb, wt_b, y, bins, ssv);
    k_stats<<<1, 256, 0, stream>>>(bins, bn_w, bn_b, ssv, n);
    k_main<1><<<grid, 256, 0, stream>>>(x, afb, wt_b, y, bins, ssv);
}

// Round 6
// 492.021 us; speedup vs baseline: 1.0574x; 1.0574x over previous
//
#include <hip/hip_runtime.h>
#include <math.h>

#define C_IN   64
#define T_DIM  256
#define V_DIM  25
#define C_OUT  256
#define S_DIM  3
#define BN_EPS 1e-5f

#define SC       (S_DIM * C_IN)          // 192
#define TW       (T_DIM * V_DIM)         // 6400
#define AP_PER_N (S_DIM * V_DIM * V_DIM) // 1875
#define LDB      200                     // sXa row stride in bf16 (400 B)
#define LDX      32                      // sX row stride in bf16 (64 B)
#define NR       32                      // atomic replica count
#define NTILE    8192                    // 64 n * 128 t-pairs
#define FRAG_SH  12288                   // shorts per tile: 24 frags * 512

typedef __attribute__((ext_vector_type(8))) short bf16x8;
typedef __attribute__((ext_vector_type(4))) float f32x4;

__device__ __forceinline__ unsigned short f2bf(float f) {
    unsigned u = __builtin_bit_cast(unsigned, f);
    unsigned r = u + 0x7fffu + ((u >> 16) & 1u);
    return (unsigned short)(r >> 16);
}

// ---------------------------------------------------------------------------
__global__ void k_prep_a(const float* __restrict__ A_pers, float* __restrict__ out_ap,
                         int total) {
    int i = blockIdx.x * 256 + threadIdx.x;
    if (i < total) out_ap[i] = tanhf(A_pers[i]);
}

// afb[n][s][nt][lane][i] = Af[v=(lane>>4)*8+i][w=nt*16+(lane&15)], 0-pad
__global__ void k_prep_afb(const float* __restrict__ A, const float* __restrict__ A_pers,
                           unsigned short* __restrict__ afb, int total) {
    int j = blockIdx.x * 256 + threadIdx.x;
    if (j >= total) return;
    int i    = j & 7;
    int lane = (j >> 3) & 63;
    int nt   = (j >> 9) & 1;
    int sn   = j >> 10;
    int s    = sn % 3;
    int n    = sn / 3;
    int v    = ((lane >> 4) << 3) + i;
    int w    = nt * 16 + (lane & 15);
    float val = 0.f;
    if (v < V_DIM && w < V_DIM)
        val = A[(s * V_DIM + v) * V_DIM + w] +
              tanhf(A_pers[((n * S_DIM + s) * V_DIM + v) * V_DIM + w]);
    afb[j] = f2bf(val);
}

// conv_w (S,C_OUT,C_IN) -> bf16 wt_b[o][sc], sc = s*64+c
__global__ void k_prep_w(const float* __restrict__ conv_w, unsigned short* __restrict__ wt_b) {
    int j = blockIdx.x * 256 + threadIdx.x;
    if (j < C_OUT * SC) {
        int o  = j / SC;
        int sc = j - o * SC;
        int s  = sc >> 6, c = sc & 63;
        wt_b[j] = f2bf(conv_w[(s * C_OUT + o) * C_IN + c]);
    }
}

// ---------------------------------------------------------------------------
// k_xa: block = (t-pair, n). Stage-1 MFMA -> sXa[tw][sc] -> dump to global in
// exact B-fragment order: xa_g[tile][(ks*4+nn)*512 + lane*8 .. +7]
// ---------------------------------------------------------------------------
__global__ __launch_bounds__(256, 4) void k_xa(const float* __restrict__ x,
                                               const unsigned short* __restrict__ afb,
                                               unsigned short* __restrict__ xa_g) {
    __shared__ __align__(16) unsigned short sX[128 * LDX];   // 8 KB
    __shared__ __align__(16) unsigned short sXa[64 * LDB];   // 25.6 KB

    const int tid  = threadIdx.x;
    const int tp   = blockIdx.x;
    const int nIdx = blockIdx.y;
    const int lane = tid & 63;
    const int wv   = tid >> 6;
    const int l15  = lane & 15;
    const int kg   = lane >> 4;

    // stage-1 B-frags
    bf16x8 bS[6];
    {
        const unsigned short* afbN = afb + (size_t)nIdx * (6 * 64 * 8);
#pragma unroll
        for (int sq = 0; sq < 6; ++sq)
            bS[sq] = *(const bf16x8*)(afbN + (sq * 64 + lane) * 8);
    }

    // zero sX K-pad cols (v=25..31) and sXa pad rows (tw=50..63)
    for (int j = tid; j < 128 * 4; j += 256) {
        int row = j >> 2, p = j & 3;
        if (p == 0) sX[row * LDX + 25] = 0;
        else ((unsigned*)sX)[row * (LDX / 2) + 12 + p] = 0;
    }
    for (int j = tid; j < 14 * (LDB / 2); j += 256)
        ((unsigned*)sXa)[50 * (LDB / 2) + j] = 0;

    // stage x -> sX bf16 (float2-vectorized)
    {
        const float* xb = x + (size_t)nIdx * C_IN * TW + (size_t)tp * 2 * V_DIM;
        for (int q = tid; q < 1600; q += 256) {
            int c = q / 25, j = q - c * 25;
            float2 v2 = *(const float2*)(xb + (size_t)c * TW + 2 * j);
            unsigned short b0 = f2bf(v2.x), b1 = f2bf(v2.y);
            if (j < 12) {
                ((unsigned*)sX)[c * LDX + j] = (unsigned)b0 | ((unsigned)b1 << 16);
            } else if (j == 12) {
                sX[(2 * c) * LDX + 24] = b0;
                sX[(2 * c + 1) * LDX]  = b1;
            } else {
                int v = 2 * j - 25;
                sX[(2 * c + 1) * LDX + v]     = b0;
                sX[(2 * c + 1) * LDX + v + 1] = b1;
            }
        }
    }
    __syncthreads();

    // stage 1: 12 MFMA/wave; paired-bf16 b32 LDS writes
#pragma unroll
    for (int sq = 0; sq < 6; ++sq) {
        int s = sq >> 1, nt = sq & 1;
        int w = nt * 16 + l15;
#pragma unroll
        for (int m2 = 0; m2 < 2; ++m2) {
            int mt = wv * 2 + m2;
            bf16x8 aX = *(const bf16x8*)(sX + (mt * 16 + l15) * LDX + kg * 8);
            f32x4 c4 = __builtin_amdgcn_mfma_f32_16x16x32_bf16(
                aX, bS[sq], (f32x4){0.f, 0.f, 0.f, 0.f}, 0, 0, 0);
            if (w < V_DIM) {
                unsigned u0 = (unsigned)f2bf(c4[0]) | ((unsigned)f2bf(c4[2]) << 16); // t=0
                unsigned u1 = (unsigned)f2bf(c4[1]) | ((unsigned)f2bf(c4[3]) << 16); // t=1
                unsigned col = s * 32 + mt * 4 + kg;
                ((unsigned*)sXa)[w * (LDB / 2) + col]           = u0;
                ((unsigned*)sXa)[(V_DIM + w) * (LDB / 2) + col] = u1;
            }
        }
    }
    __syncthreads();

    // dump sXa -> frag-ordered global (wave wv owns nn=wv, ks=0..5)
    {
        const int tile = nIdx * 128 + tp;
        unsigned short* xg = xa_g + (size_t)tile * FRAG_SH;
#pragma unroll
        for (int ks = 0; ks < 6; ++ks) {
            bf16x8 v = *(const bf16x8*)(sXa + (wv * 16 + l15) * LDB + ks * 32 + kg * 8);
            *(bf16x8*)(xg + (ks * 4 + wv) * 512 + lane * 8) = v;
        }
    }
}

// ---------------------------------------------------------------------------
// k_gsum: streaming GEMM over frag-ordered xa; channel sum/sumsq -> replica bins.
// No LDS, no barriers.
// ---------------------------------------------------------------------------
__global__ __launch_bounds__(256, 3) void k_gsum(const unsigned short* __restrict__ wt_b,
                                                 const unsigned short* __restrict__ xa_g,
                                                 float* __restrict__ bins) {
    const int tid  = threadIdx.x;
    const int tile = blockIdx.x;
    const int lane = tid & 63;
    const int wv   = tid >> 6;
    const int l15  = lane & 15;
    const int kg   = lane >> 4;

    const unsigned short* xg   = xa_g + (size_t)tile * FRAG_SH;
    const unsigned short* wrow = wt_b + (size_t)(wv * 64 + l15) * SC + kg * 8;

    f32x4 acc[4][4];
#pragma unroll
    for (int m = 0; m < 4; ++m)
#pragma unroll
        for (int nn = 0; nn < 4; ++nn) acc[m][nn] = (f32x4){0.f, 0.f, 0.f, 0.f};

#pragma unroll
    for (int ks = 0; ks < 6; ++ks) {
        bf16x8 aF[4], bF[4];
#pragma unroll
        for (int m = 0; m < 4; ++m)
            aF[m] = *(const bf16x8*)(wrow + m * 16 * SC + ks * 32);
#pragma unroll
        for (int nn = 0; nn < 4; ++nn)
            bF[nn] = *(const bf16x8*)(xg + (ks * 4 + nn) * 512 + lane * 8);
#pragma unroll
        for (int m = 0; m < 4; ++m)
#pragma unroll
            for (int nn = 0; nn < 4; ++nn)
                acc[m][nn] = __builtin_amdgcn_mfma_f32_16x16x32_bf16(aF[m], bF[nn], acc[m][nn], 0, 0, 0);
    }

    const int wbase = wv * 64;
    const int rep   = tile & (NR - 1);
    float* b0 = bins + rep * 2 * C_OUT;
#pragma unroll
    for (int m = 0; m < 4; ++m) {
#pragma unroll
        for (int r = 0; r < 4; ++r) {
            float v0 = acc[m][0][r], v1 = acc[m][1][r], v2 = acc[m][2][r];
            float s1 = v0 + v1 + v2;
            float s2 = v0 * v0 + v1 * v1 + v2 * v2;
            if (l15 < 2) {                       // tw = 48+l15 < 50
                float v3 = acc[m][3][r];
                s1 += v3;
                s2 += v3 * v3;
            }
#pragma unroll
            for (int off = 1; off < 16; off <<= 1) {
                s1 += __shfl_xor(s1, off, 64);
                s2 += __shfl_xor(s2, off, 64);
            }
            if (l15 == 0) {
                int o = wbase + m * 16 + kg * 4 + r;
                atomicAdd(&b0[o], s1);
                atomicAdd(&b0[C_OUT + o], s2);
            }
        }
    }
}

// ---------------------------------------------------------------------------
// k_gy: streaming GEMM + fused BN/ReLU; y staged through LDS for long write runs.
// ---------------------------------------------------------------------------
__global__ __launch_bounds__(256, 3) void k_gy(const unsigned short* __restrict__ wt_b,
                                               const unsigned short* __restrict__ xa_g,
                                               const float2* __restrict__ ssv,
                                               float* __restrict__ y) {
    __shared__ float sY[C_OUT * 50];   // 51.2 KB

    const int tid  = threadIdx.x;
    const int tile = blockIdx.x;
    const int nIdx = tile >> 7;
    const int tp   = tile & 127;
    const int lane = tid & 63;
    const int wv   = tid >> 6;
    const int l15  = lane & 15;
    const int kg   = lane >> 4;

    const unsigned short* xg   = xa_g + (size_t)tile * FRAG_SH;
    const unsigned short* wrow = wt_b + (size_t)(wv * 64 + l15) * SC + kg * 8;

    f32x4 acc[4][4];
#pragma unroll
    for (int m = 0; m < 4; ++m)
#pragma unroll
        for (int nn = 0; nn < 4; ++nn) acc[m][nn] = (f32x4){0.f, 0.f, 0.f, 0.f};

#pragma unroll
    for (int ks = 0; ks < 6; ++ks) {
        bf16x8 aF[4], bF[4];
#pragma unroll
        for (int m = 0; m < 4; ++m)
            aF[m] = *(const bf16x8*)(wrow + m * 16 * SC + ks * 32);
#pragma unroll
        for (int nn = 0; nn < 4; ++nn)
            bF[nn] = *(const bf16x8*)(xg + (ks * 4 + nn) * 512 + lane * 8);
#pragma unroll
        for (int m = 0; m < 4; ++m)
#pragma unroll
            for (int nn = 0; nn < 4; ++nn)
                acc[m][nn] = __builtin_amdgcn_mfma_f32_16x16x32_bf16(aF[m], bF[nn], acc[m][nn], 0, 0, 0);
    }

    // BN+ReLU into LDS tile [o][tw<50]
    const int wbase = wv * 64;
#pragma unroll
    for (int m = 0; m < 4; ++m) {
#pragma unroll
        for (int r = 0; r < 4; ++r) {
            int o = wbase + m * 16 + kg * 4 + r;
            float2 sh = ssv[o];
            float* sp = sY + o * 50 + l15;
            sp[0]  = fmaxf(fmaf(acc[m][0][r], sh.x, sh.y), 0.f);
            sp[16] = fmaxf(fmaf(acc[m][1][r], sh.x, sh.y), 0.f);
            sp[32] = fmaxf(fmaf(acc[m][2][r], sh.x, sh.y), 0.f);
            if (l15 < 2)
                sp[48] = fmaxf(fmaf(acc[m][3][r], sh.x, sh.y), 0.f);
        }
    }
    __syncthreads();

    // coalesced dump: 6400 float2, ~200 B runs per o-row
    float* ydst = y + (size_t)nIdx * C_OUT * TW + (size_t)tp * 50;
#pragma unroll 5
    for (int q = tid; q < 6400; q += 256) {
        int o = q / 25, jj = q - o * 25;
        float2 v = *(const float2*)(sY + o * 50 + jj * 2);
        *(float2*)(ydst + (size_t)o * TW + jj * 2) = v;
    }
}

// ---------------------------------------------------------------------------
__global__ void k_stats(const float* __restrict__ bins, const float* __restrict__ bn_w,
                        const float* __restrict__ bn_b, float2* __restrict__ ssv, int n) {
    int o = threadIdx.x;
    float s1 = 0.f, s2 = 0.f;
    for (int rp = 0; rp < NR; ++rp) {
        s1 += bins[rp * 2 * C_OUT + o];
        s2 += bins[rp * 2 * C_OUT + C_OUT + o];
    }
    float cnt   = (float)n * (float)TW;
    float mean  = s1 / cnt;
    float var   = s2 / cnt - mean * mean;
    float scale = bn_w[o] * rsqrtf(var + BN_EPS);
    ssv[o] = make_float2(scale, bn_b[o] - mean * scale);
}

// ---------------------------------------------------------------------------
// Fallback fused kernel (R4, known-good) for small ws_size
// ---------------------------------------------------------------------------
template <int PASS>
__global__ __launch_bounds__(256, 4) void k_fused(const float* __restrict__ x,
                                                  const unsigned short* __restrict__ afb,
                                                  const unsigned short* __restrict__ wt_b,
                                                  float* __restrict__ y,
                                                  float* __restrict__ bins,
                                                  const float2* __restrict__ ssv) {
    __shared__ __align__(16) unsigned short sX[128 * LDX];
    __shared__ __align__(16) unsigned short sXa[64 * LDB];

    const int tid  = threadIdx.x;
    const int nIdx = blockIdx.y;
    const int t0   = blockIdx.x * 2;
    const int lane = tid & 63;
    const int wv   = tid >> 6;
    const int l15  = lane & 15;
    const int kg   = lane >> 4;

    bf16x8 bS[6];
    {
        const unsigned short* afbN = afb + (size_t)nIdx * (6 * 64 * 8);
#pragma unroll
        for (int sq = 0; sq < 6; ++sq)
            bS[sq] = *(const bf16x8*)(afbN + (sq * 64 + lane) * 8);
    }
    for (int j = tid; j < 128 * 4; j += 256) {
        int row = j >> 2, p = j & 3;
        if (p == 0) sX[row * LDX + 25] = 0;
        else ((unsigned*)sX)[row * (LDX / 2) + 12 + p] = 0;
    }
    {
        const float* xb = x + (size_t)nIdx * C_IN * TW + (size_t)t0 * V_DIM;
        for (int q = tid; q < 1600; q += 256) {
            int c = q / 25, j = q - c * 25;
            float2 v2 = *(const float2*)(xb + (size_t)c * TW + 2 * j);
            unsigned short b0 = f2bf(v2.x), b1 = f2bf(v2.y);
            if (j < 12) {
                ((unsigned*)sX)[c * LDX + j] = (unsigned)b0 | ((unsigned)b1 << 16);
            } else if (j == 12) {
                sX[(2 * c) * LDX + 24] = b0;
                sX[(2 * c + 1) * LDX]  = b1;
            } else {
                int v = 2 * j - 25;
                sX[(2 * c + 1) * LDX + v]     = b0;
                sX[(2 * c + 1) * LDX + v + 1] = b1;
            }
        }
    }
    __syncthreads();
#pragma unroll
    for (int sq = 0; sq < 6; ++sq) {
        int s = sq >> 1, nt = sq & 1;
        int w = nt * 16 + l15;
#pragma unroll
        for (int m2 = 0; m2 < 2; ++m2) {
            int mt = wv * 2 + m2;
            bf16x8 aX = *(const bf16x8*)(sX + (mt * 16 + l15) * LDX + kg * 8);
            f32x4 c4 = __builtin_amdgcn_mfma_f32_16x16x32_bf16(
                aX, bS[sq], (f32x4){0.f, 0.f, 0.f, 0.f}, 0, 0, 0);
            if (w < V_DIM) {
                unsigned u0 = (unsigned)f2bf(c4[0]) | ((unsigned)f2bf(c4[2]) << 16);
                unsigned u1 = (unsigned)f2bf(c4[1]) | ((unsigned)f2bf(c4[3]) << 16);
                unsigned col = s * 32 + mt * 4 + kg;
                ((unsigned*)sXa)[w * (LDB / 2) + col]           = u0;
                ((unsigned*)sXa)[(V_DIM + w) * (LDB / 2) + col] = u1;
            }
        }
    }
    __syncthreads();

    f32x4 acc[4][4];
#pragma unroll
    for (int m = 0; m < 4; ++m)
#pragma unroll
        for (int nn = 0; nn < 4; ++nn) acc[m][nn] = (f32x4){0.f, 0.f, 0.f, 0.f};

    const unsigned short* wrow = wt_b + (size_t)(wv * 64 + l15) * SC + kg * 8;
#pragma unroll
    for (int ks = 0; ks < 6; ++ks) {
        bf16x8 aF[4], bF[4];
#pragma unroll
        for (int m = 0; m < 4; ++m)
            aF[m] = *(const bf16x8*)(wrow + m * 16 * SC + ks * 32);
#pragma unroll
        for (int nn = 0; nn < 4; ++nn)
            bF[nn] = *(const bf16x8*)(sXa + (nn * 16 + l15) * LDB + ks * 32 + kg * 8);
#pragma unroll
        for (int m = 0; m < 4; ++m)
#pragma unroll
            for (int nn = 0; nn < 4; ++nn)
                acc[m][nn] = __builtin_amdgcn_mfma_f32_16x16x32_bf16(aF[m], bF[nn], acc[m][nn], 0, 0, 0);
    }

    const int wbase = wv * 64;
    if (PASS == 0) {
        const int rep = (blockIdx.y * gridDim.x + blockIdx.x) & (NR - 1);
        float* b0 = bins + rep * 2 * C_OUT;
#pragma unroll
        for (int m = 0; m < 4; ++m) {
#pragma unroll
            for (int r = 0; r < 4; ++r) {
                float v0 = acc[m][0][r], v1 = acc[m][1][r], v2 = acc[m][2][r];
                float s1 = v0 + v1 + v2;
                float s2 = v0 * v0 + v1 * v1 + v2 * v2;
                if (l15 < 2) {
                    float v3 = acc[m][3][r];
                    s1 += v3;
                    s2 += v3 * v3;
                }
#pragma unroll
                for (int off = 1; off < 16; off <<= 1) {
                    s1 += __shfl_xor(s1, off, 64);
                    s2 += __shfl_xor(s2, off, 64);
                }
                if (l15 == 0) {
                    int o = wbase + m * 16 + kg * 4 + r;
                    atomicAdd(&b0[o], s1);
                    atomicAdd(&b0[C_OUT + o], s2);
                }
            }
        }
    } else {
        const size_t ybase = (size_t)nIdx * C_OUT * TW + (size_t)t0 * V_DIM;
#pragma unroll
        for (int m = 0; m < 4; ++m) {
#pragma unroll
            for (int r = 0; r < 4; ++r) {
                int o = wbase + m * 16 + kg * 4 + r;
                float2 sh = ssv[o];
                float* yp = y + ybase + (size_t)o * TW + l15;
                yp[0]  = fmaxf(fmaf(acc[m][0][r], sh.x, sh.y), 0.f);
                yp[16] = fmaxf(fmaf(acc[m][1][r], sh.x, sh.y), 0.f);
                yp[32] = fmaxf(fmaf(acc[m][2][r], sh.x, sh.y), 0.f);
                if (l15 < 2)
                    yp[48] = fmaxf(fmaf(acc[m][3][r], sh.x, sh.y), 0.f);
            }
        }
    }
}

// ---------------------------------------------------------------------------
extern "C" void kernel_launch(void* const* d_in, const int* in_sizes, int n_in,
                              void* d_out, int out_size, void* d_ws, size_t ws_size,
                              hipStream_t stream) {
    const float* x      = (const float*)d_in[0];
    const float* A      = (const float*)d_in[1];
    const float* A_pers = (const float*)d_in[2];
    const float* conv_w = (const float*)d_in[3];
    // d_in[4] = conv_b: cancels under training-mode BatchNorm -> unused
    const float* bn_w   = (const float*)d_in[5];
    const float* bn_b   = (const float*)d_in[6];

    const int n = in_sizes[0] / (C_IN * TW);   // 64

    float* out_ap = (float*)d_out;
    float* y      = (float*)d_out + (size_t)n * AP_PER_N;

    // ws layout
    float*  bins = (float*)d_ws;                                    // 64 KB
    float2* ssv  = (float2*)(bins + NR * 2 * C_OUT);                // 2 KB
    unsigned short* afb  = (unsigned short*)((char*)(ssv + C_OUT)); // 384 KB
    unsigned short* wt_b = afb + (size_t)n * 6 * 64 * 8;            // 96 KB
    unsigned short* xa_g = wt_b + (size_t)C_OUT * SC;               // 201.3 MB
    const size_t need = (size_t)(NR * 2 * C_OUT) * 4 + C_OUT * 8 +
                        ((size_t)n * 6 * 64 * 8 + (size_t)C_OUT * SC +
                         (size_t)NTILE * FRAG_SH) * 2;

    hipMemsetAsync(bins, 0, NR * 2 * C_OUT * sizeof(float), stream);

    int totA = n * AP_PER_N;
    k_prep_a<<<(totA + 255) / 256, 256, 0, stream>>>(A_pers, out_ap, totA);
    int totF = n * 6 * 64 * 8;
    k_prep_afb<<<(totF + 255) / 256, 256, 0, stream>>>(A, A_pers, afb, totF);
    k_prep_w<<<(C_OUT * SC + 255) / 256, 256, 0, stream>>>(conv_w, wt_b);

    if (ws_size >= need) {
        k_xa<<<dim3(T_DIM / 2, n), 256, 0, stream>>>(x, afb, xa_g);
        k_gsum<<<NTILE, 256, 0, stream>>>(wt_b, xa_g, bins);
        k_stats<<<1, 256, 0, stream>>>(bins, bn_w, bn_b, ssv, n);
        k_gy<<<NTILE, 256, 0, stream>>>(wt_b, xa_g, ssv, y);
    } else {
        dim3 grid(T_DIM / 2, n);
        k_fused<0><<<grid, 256, 0, stream>>>(x, afb, wt_b, y, bins, ssv);
        k_stats<<<1, 256, 0, stream>>>(bins, bn_w, bn_b, ssv, n);
        k_fused<1><<<grid, 256, 0, stream>>>(x, afb, wt_b, y, bins, ssv);
    }
}

// Round 7
// 486.162 us; speedup vs baseline: 1.0702x; 1.0121x over previous
//
#include <hip/hip_runtime.h>
#include <math.h>

#define C_IN   64
#define T_DIM  256
#define V_DIM  25
#define C_OUT  256
#define S_DIM  3
#define BN_EPS 1e-5f

#define SC       (S_DIM * C_IN)          // 192
#define TW       (T_DIM * V_DIM)         // 6400
#define AP_PER_N (S_DIM * V_DIM * V_DIM) // 1875
#define LDB      200                     // sXa row stride in bf16 (400 B)
#define LDX      32                      // sX row stride in bf16 (64 B)
#define NR       32                      // atomic replica count
#define NTILE    8192                    // 64 n * 128 t-pairs
#define FRAG_SH  12288                   // shorts per tile: 24 frags * 512

#define NBINS    (NR * 2 * C_OUT)        // 16384
#define NAP      (64 * AP_PER_N)         // 120000 (n=64)
#define NAFB     (64 * 6 * 64 * 8)       // 196608
#define NWT      (C_OUT * SC)            // 49152
#define PREP_TOT (NBINS + NAP + NAFB + NWT)

typedef __attribute__((ext_vector_type(8))) short bf16x8;
typedef __attribute__((ext_vector_type(4))) float f32x4;

__device__ __forceinline__ unsigned short f2bf(float f) {
    unsigned u = __builtin_bit_cast(unsigned, f);
    unsigned r = u + 0x7fffu + ((u >> 16) & 1u);
    return (unsigned short)(r >> 16);
}

// ---------------------------------------------------------------------------
// Merged prep: zero bins | out_ap=tanh | afb pack | wt_b pack — one launch,
// no hipMemsetAsync graph node (a 64KB fill node cost ~240us/replay in R6).
// ---------------------------------------------------------------------------
__global__ void k_prep(const float* __restrict__ A, const float* __restrict__ A_pers,
                       const float* __restrict__ conv_w,
                       float* __restrict__ bins, float* __restrict__ out_ap,
                       unsigned short* __restrict__ afb, unsigned short* __restrict__ wt_b) {
    int i = blockIdx.x * 256 + threadIdx.x;
    if (i < NBINS) {
        bins[i] = 0.f;
        return;
    }
    i -= NBINS;
    if (i < NAP) {
        out_ap[i] = tanhf(A_pers[i]);
        return;
    }
    i -= NAP;
    if (i < NAFB) {
        int j    = i;
        int k    = j & 7;
        int lane = (j >> 3) & 63;
        int nt   = (j >> 9) & 1;
        int sn   = j >> 10;
        int s    = sn % 3;
        int n    = sn / 3;
        int v    = ((lane >> 4) << 3) + k;
        int w    = nt * 16 + (lane & 15);
        float val = 0.f;
        if (v < V_DIM && w < V_DIM)
            val = A[(s * V_DIM + v) * V_DIM + w] +
                  tanhf(A_pers[((n * S_DIM + s) * V_DIM + v) * V_DIM + w]);
        afb[j] = f2bf(val);
        return;
    }
    i -= NAFB;
    if (i < NWT) {
        int o  = i / SC;
        int sc = i - o * SC;
        int s  = sc >> 6, c = sc & 63;
        wt_b[i] = f2bf(conv_w[(s * C_OUT + o) * C_IN + c]);
    }
}

// ---------------------------------------------------------------------------
// k_xa: block = (t-pair, n). Stage-1 MFMA -> sXa[tw][sc] -> dump to global in
// exact B-fragment order: xa_g[tile][(ks*4+nn)*512 + lane*8 .. +7]
// ---------------------------------------------------------------------------
__global__ __launch_bounds__(256, 4) void k_xa(const float* __restrict__ x,
                                               const unsigned short* __restrict__ afb,
                                               unsigned short* __restrict__ xa_g) {
    __shared__ __align__(16) unsigned short sX[128 * LDX];   // 8 KB
    __shared__ __align__(16) unsigned short sXa[64 * LDB];   // 25.6 KB

    const int tid  = threadIdx.x;
    const int tp   = blockIdx.x;
    const int nIdx = blockIdx.y;
    const int lane = tid & 63;
    const int wv   = tid >> 6;
    const int l15  = lane & 15;
    const int kg   = lane >> 4;

    // stage-1 B-frags
    bf16x8 bS[6];
    {
        const unsigned short* afbN = afb + (size_t)nIdx * (6 * 64 * 8);
#pragma unroll
        for (int sq = 0; sq < 6; ++sq)
            bS[sq] = *(const bf16x8*)(afbN + (sq * 64 + lane) * 8);
    }

    // zero sX K-pad cols (v=25..31) and sXa pad rows (tw=50..63)
    for (int j = tid; j < 128 * 4; j += 256) {
        int row = j >> 2, p = j & 3;
        if (p == 0) sX[row * LDX + 25] = 0;
        else ((unsigned*)sX)[row * (LDX / 2) + 12 + p] = 0;
    }
    for (int j = tid; j < 14 * (LDB / 2); j += 256)
        ((unsigned*)sXa)[50 * (LDB / 2) + j] = 0;

    // stage x -> sX bf16 (float2-vectorized)
    {
        const float* xb = x + (size_t)nIdx * C_IN * TW + (size_t)tp * 2 * V_DIM;
        for (int q = tid; q < 1600; q += 256) {
            int c = q / 25, j = q - c * 25;
            float2 v2 = *(const float2*)(xb + (size_t)c * TW + 2 * j);
            unsigned short b0 = f2bf(v2.x), b1 = f2bf(v2.y);
            if (j < 12) {
                ((unsigned*)sX)[c * LDX + j] = (unsigned)b0 | ((unsigned)b1 << 16);
            } else if (j == 12) {
                sX[(2 * c) * LDX + 24] = b0;
                sX[(2 * c + 1) * LDX]  = b1;
            } else {
                int v = 2 * j - 25;
                sX[(2 * c + 1) * LDX + v]     = b0;
                sX[(2 * c + 1) * LDX + v + 1] = b1;
            }
        }
    }
    __syncthreads();

    // stage 1: 12 MFMA/wave; paired-bf16 b32 LDS writes
#pragma unroll
    for (int sq = 0; sq < 6; ++sq) {
        int s = sq >> 1, nt = sq & 1;
        int w = nt * 16 + l15;
#pragma unroll
        for (int m2 = 0; m2 < 2; ++m2) {
            int mt = wv * 2 + m2;
            bf16x8 aX = *(const bf16x8*)(sX + (mt * 16 + l15) * LDX + kg * 8);
            f32x4 c4 = __builtin_amdgcn_mfma_f32_16x16x32_bf16(
                aX, bS[sq], (f32x4){0.f, 0.f, 0.f, 0.f}, 0, 0, 0);
            if (w < V_DIM) {
                unsigned u0 = (unsigned)f2bf(c4[0]) | ((unsigned)f2bf(c4[2]) << 16); // t=0
                unsigned u1 = (unsigned)f2bf(c4[1]) | ((unsigned)f2bf(c4[3]) << 16); // t=1
                unsigned col = s * 32 + mt * 4 + kg;
                ((unsigned*)sXa)[w * (LDB / 2) + col]           = u0;
                ((unsigned*)sXa)[(V_DIM + w) * (LDB / 2) + col] = u1;
            }
        }
    }
    __syncthreads();

    // dump sXa -> frag-ordered global (wave wv owns nn=wv, ks=0..5)
    {
        const int tile = nIdx * 128 + tp;
        unsigned short* xg = xa_g + (size_t)tile * FRAG_SH;
#pragma unroll
        for (int ks = 0; ks < 6; ++ks) {
            bf16x8 v = *(const bf16x8*)(sXa + (wv * 16 + l15) * LDB + ks * 32 + kg * 8);
            *(bf16x8*)(xg + (ks * 4 + wv) * 512 + lane * 8) = v;
        }
    }
}

// ---------------------------------------------------------------------------
// k_gsum: streaming GEMM over frag-ordered xa; channel sum/sumsq -> replica bins.
// No LDS, no barriers.
// ---------------------------------------------------------------------------
__global__ __launch_bounds__(256, 3) void k_gsum(const unsigned short* __restrict__ wt_b,
                                                 const unsigned short* __restrict__ xa_g,
                                                 float* __restrict__ bins) {
    const int tid  = threadIdx.x;
    const int tile = blockIdx.x;
    const int lane = tid & 63;
    const int wv   = tid >> 6;
    const int l15  = lane & 15;
    const int kg   = lane >> 4;

    const unsigned short* xg   = xa_g + (size_t)tile * FRAG_SH;
    const unsigned short* wrow = wt_b + (size_t)(wv * 64 + l15) * SC + kg * 8;

    f32x4 acc[4][4];
#pragma unroll
    for (int m = 0; m < 4; ++m)
#pragma unroll
        for (int nn = 0; nn < 4; ++nn) acc[m][nn] = (f32x4){0.f, 0.f, 0.f, 0.f};

#pragma unroll
    for (int ks = 0; ks < 6; ++ks) {
        bf16x8 aF[4], bF[4];
#pragma unroll
        for (int m = 0; m < 4; ++m)
            aF[m] = *(const bf16x8*)(wrow + m * 16 * SC + ks * 32);
#pragma unroll
        for (int nn = 0; nn < 4; ++nn)
            bF[nn] = *(const bf16x8*)(xg + (ks * 4 + nn) * 512 + lane * 8);
#pragma unroll
        for (int m = 0; m < 4; ++m)
#pragma unroll
            for (int nn = 0; nn < 4; ++nn)
                acc[m][nn] = __builtin_amdgcn_mfma_f32_16x16x32_bf16(aF[m], bF[nn], acc[m][nn], 0, 0, 0);
    }

    const int wbase = wv * 64;
    const int rep   = tile & (NR - 1);
    float* b0 = bins + rep * 2 * C_OUT;
#pragma unroll
    for (int m = 0; m < 4; ++m) {
#pragma unroll
        for (int r = 0; r < 4; ++r) {
            float v0 = acc[m][0][r], v1 = acc[m][1][r], v2 = acc[m][2][r];
            float s1 = v0 + v1 + v2;
            float s2 = v0 * v0 + v1 * v1 + v2 * v2;
            if (l15 < 2) {                       // tw = 48+l15 < 50
                float v3 = acc[m][3][r];
                s1 += v3;
                s2 += v3 * v3;
            }
#pragma unroll
            for (int off = 1; off < 16; off <<= 1) {
                s1 += __shfl_xor(s1, off, 64);
                s2 += __shfl_xor(s2, off, 64);
            }
            if (l15 == 0) {
                int o = wbase + m * 16 + kg * 4 + r;
                atomicAdd(&b0[o], s1);
                atomicAdd(&b0[C_OUT + o], s2);
            }
        }
    }
}

// ---------------------------------------------------------------------------
// k_gy: streaming GEMM + fused BN/ReLU; y staged through LDS for long write runs.
// ---------------------------------------------------------------------------
__global__ __launch_bounds__(256, 3) void k_gy(const unsigned short* __restrict__ wt_b,
                                               const unsigned short* __restrict__ xa_g,
                                               const float2* __restrict__ ssv,
                                               float* __restrict__ y) {
    __shared__ float sY[C_OUT * 50];   // 51.2 KB

    const int tid  = threadIdx.x;
    const int tile = blockIdx.x;
    const int nIdx = tile >> 7;
    const int tp   = tile & 127;
    const int lane = tid & 63;
    const int wv   = tid >> 6;
    const int l15  = lane & 15;
    const int kg   = lane >> 4;

    const unsigned short* xg   = xa_g + (size_t)tile * FRAG_SH;
    const unsigned short* wrow = wt_b + (size_t)(wv * 64 + l15) * SC + kg * 8;

    f32x4 acc[4][4];
#pragma unroll
    for (int m = 0; m < 4; ++m)
#pragma unroll
        for (int nn = 0; nn < 4; ++nn) acc[m][nn] = (f32x4){0.f, 0.f, 0.f, 0.f};

#pragma unroll
    for (int ks = 0; ks < 6; ++ks) {
        bf16x8 aF[4], bF[4];
#pragma unroll
        for (int m = 0; m < 4; ++m)
            aF[m] = *(const bf16x8*)(wrow + m * 16 * SC + ks * 32);
#pragma unroll
        for (int nn = 0; nn < 4; ++nn)
            bF[nn] = *(const bf16x8*)(xg + (ks * 4 + nn) * 512 + lane * 8);
#pragma unroll
        for (int m = 0; m < 4; ++m)
#pragma unroll
            for (int nn = 0; nn < 4; ++nn)
                acc[m][nn] = __builtin_amdgcn_mfma_f32_16x16x32_bf16(aF[m], bF[nn], acc[m][nn], 0, 0, 0);
    }

    // BN+ReLU into LDS tile [o][tw<50]
    const int wbase = wv * 64;
#pragma unroll
    for (int m = 0; m < 4; ++m) {
#pragma unroll
        for (int r = 0; r < 4; ++r) {
            int o = wbase + m * 16 + kg * 4 + r;
            float2 sh = ssv[o];
            float* sp = sY + o * 50 + l15;
            sp[0]  = fmaxf(fmaf(acc[m][0][r], sh.x, sh.y), 0.f);
            sp[16] = fmaxf(fmaf(acc[m][1][r], sh.x, sh.y), 0.f);
            sp[32] = fmaxf(fmaf(acc[m][2][r], sh.x, sh.y), 0.f);
            if (l15 < 2)
                sp[48] = fmaxf(fmaf(acc[m][3][r], sh.x, sh.y), 0.f);
        }
    }
    __syncthreads();

    // coalesced dump: 6400 float2, 200 B runs per o-row
    float* ydst = y + (size_t)nIdx * C_OUT * TW + (size_t)tp * 50;
#pragma unroll 5
    for (int q = tid; q < 6400; q += 256) {
        int o = q / 25, jj = q - o * 25;
        float2 v = *(const float2*)(sY + o * 50 + jj * 2);
        *(float2*)(ydst + (size_t)o * TW + jj * 2) = v;
    }
}

// ---------------------------------------------------------------------------
__global__ void k_stats(const float* __restrict__ bins, const float* __restrict__ bn_w,
                        const float* __restrict__ bn_b, float2* __restrict__ ssv, int n) {
    int o = threadIdx.x;
    float s1 = 0.f, s2 = 0.f;
    for (int rp = 0; rp < NR; ++rp) {
        s1 += bins[rp * 2 * C_OUT + o];
        s2 += bins[rp * 2 * C_OUT + C_OUT + o];
    }
    float cnt   = (float)n * (float)TW;
    float mean  = s1 / cnt;
    float var   = s2 / cnt - mean * mean;
    float scale = bn_w[o] * rsqrtf(var + BN_EPS);
    ssv[o] = make_float2(scale, bn_b[o] - mean * scale);
}

// ---------------------------------------------------------------------------
// Fallback fused kernel (R4, known-good) for small ws_size
// ---------------------------------------------------------------------------
template <int PASS>
__global__ __launch_bounds__(256, 4) void k_fused(const float* __restrict__ x,
                                                  const unsigned short* __restrict__ afb,
                                                  const unsigned short* __restrict__ wt_b,
                                                  float* __restrict__ y,
                                                  float* __restrict__ bins,
                                                  const float2* __restrict__ ssv) {
    __shared__ __align__(16) unsigned short sX[128 * LDX];
    __shared__ __align__(16) unsigned short sXa[64 * LDB];

    const int tid  = threadIdx.x;
    const int nIdx = blockIdx.y;
    const int t0   = blockIdx.x * 2;
    const int lane = tid & 63;
    const int wv   = tid >> 6;
    const int l15  = lane & 15;
    const int kg   = lane >> 4;

    bf16x8 bS[6];
    {
        const unsigned short* afbN = afb + (size_t)nIdx * (6 * 64 * 8);
#pragma unroll
        for (int sq = 0; sq < 6; ++sq)
            bS[sq] = *(const bf16x8*)(afbN + (sq * 64 + lane) * 8);
    }
    for (int j = tid; j < 128 * 4; j += 256) {
        int row = j >> 2, p = j & 3;
        if (p == 0) sX[row * LDX + 25] = 0;
        else ((unsigned*)sX)[row * (LDX / 2) + 12 + p] = 0;
    }
    {
        const float* xb = x + (size_t)nIdx * C_IN * TW + (size_t)t0 * V_DIM;
        for (int q = tid; q < 1600; q += 256) {
            int c = q / 25, j = q - c * 25;
            float2 v2 = *(const float2*)(xb + (size_t)c * TW + 2 * j);
            unsigned short b0 = f2bf(v2.x), b1 = f2bf(v2.y);
            if (j < 12) {
                ((unsigned*)sX)[c * LDX + j] = (unsigned)b0 | ((unsigned)b1 << 16);
            } else if (j == 12) {
                sX[(2 * c) * LDX + 24] = b0;
                sX[(2 * c + 1) * LDX]  = b1;
            } else {
                int v = 2 * j - 25;
                sX[(2 * c + 1) * LDX + v]     = b0;
                sX[(2 * c + 1) * LDX + v + 1] = b1;
            }
        }
    }
    __syncthreads();
#pragma unroll
    for (int sq = 0; sq < 6; ++sq) {
        int s = sq >> 1, nt = sq & 1;
        int w = nt * 16 + l15;
#pragma unroll
        for (int m2 = 0; m2 < 2; ++m2) {
            int mt = wv * 2 + m2;
            bf16x8 aX = *(const bf16x8*)(sX + (mt * 16 + l15) * LDX + kg * 8);
            f32x4 c4 = __builtin_amdgcn_mfma_f32_16x16x32_bf16(
                aX, bS[sq], (f32x4){0.f, 0.f, 0.f, 0.f}, 0, 0, 0);
            if (w < V_DIM) {
                unsigned u0 = (unsigned)f2bf(c4[0]) | ((unsigned)f2bf(c4[2]) << 16);
                unsigned u1 = (unsigned)f2bf(c4[1]) | ((unsigned)f2bf(c4[3]) << 16);
                unsigned col = s * 32 + mt * 4 + kg;
                ((unsigned*)sXa)[w * (LDB / 2) + col]           = u0;
                ((unsigned*)sXa)[(V_DIM + w) * (LDB / 2) + col] = u1;
            }
        }
    }
    __syncthreads();

    f32x4 acc[4][4];
#pragma unroll
    for (int m = 0; m < 4; ++m)
#pragma unroll
        for (int nn = 0; nn < 4; ++nn) acc[m][nn] = (f32x4){0.f, 0.f, 0.f, 0.f};

    const unsigned short* wrow = wt_b + (size_t)(wv * 64 + l15) * SC + kg * 8;
#pragma unroll
    for (int ks = 0; ks < 6; ++ks) {
        bf16x8 aF[4], bF[4];
#pragma unroll
        for (int m = 0; m < 4; ++m)
            aF[m] = *(const bf16x8*)(wrow + m * 16 * SC + ks * 32);
#pragma unroll
        for (int nn = 0; nn < 4; ++nn)
            bF[nn] = *(const bf16x8*)(sXa + (nn * 16 + l15) * LDB + ks * 32 + kg * 8);
#pragma unroll
        for (int m = 0; m < 4; ++m)
#pragma unroll
            for (int nn = 0; nn < 4; ++nn)
                acc[m][nn] = __builtin_amdgcn_mfma_f32_16x16x32_bf16(aF[m], bF[nn], acc[m][nn], 0, 0, 0);
    }

    const int wbase = wv * 64;
    if (PASS == 0) {
        const int rep = (blockIdx.y * gridDim.x + blockIdx.x) & (NR - 1);
        float* b0 = bins + rep * 2 * C_OUT;
#pragma unroll
        for (int m = 0; m < 4; ++m) {
#pragma unroll
            for (int r = 0; r < 4; ++r) {
                float v0 = acc[m][0][r], v1 = acc[m][1][r], v2 = acc[m][2][r];
                float s1 = v0 + v1 + v2;
                float s2 = v0 * v0 + v1 * v1 + v2 * v2;
                if (l15 < 2) {
                    float v3 = acc[m][3][r];
                    s1 += v3;
                    s2 += v3 * v3;
                }
#pragma unroll
                for (int off = 1; off < 16; off <<= 1) {
                    s1 += __shfl_xor(s1, off, 64);
                    s2 += __shfl_xor(s2, off, 64);
                }
                if (l15 == 0) {
                    int o = wbase + m * 16 + kg * 4 + r;
                    atomicAdd(&b0[o], s1);
                    atomicAdd(&b0[C_OUT + o], s2);
                }
            }
        }
    } else {
        const size_t ybase = (size_t)nIdx * C_OUT * TW + (size_t)t0 * V_DIM;
#pragma unroll
        for (int m = 0; m < 4; ++m) {
#pragma unroll
            for (int r = 0; r < 4; ++r) {
                int o = wbase + m * 16 + kg * 4 + r;
                float2 sh = ssv[o];
                float* yp = y + ybase + (size_t)o * TW + l15;
                yp[0]  = fmaxf(fmaf(acc[m][0][r], sh.x, sh.y), 0.f);
                yp[16] = fmaxf(fmaf(acc[m][1][r], sh.x, sh.y), 0.f);
                yp[32] = fmaxf(fmaf(acc[m][2][r], sh.x, sh.y), 0.f);
                if (l15 < 2)
                    yp[48] = fmaxf(fmaf(acc[m][3][r], sh.x, sh.y), 0.f);
            }
        }
    }
}

// ---------------------------------------------------------------------------
extern "C" void kernel_launch(void* const* d_in, const int* in_sizes, int n_in,
                              void* d_out, int out_size, void* d_ws, size_t ws_size,
                              hipStream_t stream) {
    const float* x      = (const float*)d_in[0];
    const float* A      = (const float*)d_in[1];
    const float* A_pers = (const float*)d_in[2];
    const float* conv_w = (const float*)d_in[3];
    // d_in[4] = conv_b: cancels under training-mode BatchNorm -> unused
    const float* bn_w   = (const float*)d_in[5];
    const float* bn_b   = (const float*)d_in[6];

    const int n = in_sizes[0] / (C_IN * TW);   // 64

    float* out_ap = (float*)d_out;
    float* y      = (float*)d_out + (size_t)n * AP_PER_N;

    // ws layout
    float*  bins = (float*)d_ws;                                    // 64 KB
    float2* ssv  = (float2*)(bins + NBINS);                         // 2 KB
    unsigned short* afb  = (unsigned short*)((char*)(ssv + C_OUT)); // 384 KB
    unsigned short* wt_b = afb + (size_t)NAFB;                      // 96 KB
    unsigned short* xa_g = wt_b + (size_t)NWT;                      // 201.3 MB
    const size_t need = (size_t)NBINS * 4 + C_OUT * 8 +
                        ((size_t)NAFB + NWT + (size_t)NTILE * FRAG_SH) * 2;

    // one merged prep launch: zero bins + out_ap + afb + wt_b (no memset node)
    k_prep<<<(PREP_TOT + 255) / 256, 256, 0, stream>>>(A, A_pers, conv_w,
                                                       bins, out_ap, afb, wt_b);

    if (ws_size >= need) {
        k_xa<<<dim3(T_DIM / 2, n), 256, 0, stream>>>(x, afb, xa_g);
        k_gsum<<<NTILE, 256, 0, stream>>>(wt_b, xa_g, bins);
        k_stats<<<1, 256, 0, stream>>>(bins, bn_w, bn_b, ssv, n);
        k_gy<<<NTILE, 256, 0, stream>>>(wt_b, xa_g, ssv, y);
    } else {
        dim3 grid(T_DIM / 2, n);
        k_fused<0><<<grid, 256, 0, stream>>>(x, afb, wt_b, y, bins, ssv);
        k_stats<<<1, 256, 0, stream>>>(bins, bn_w, bn_b, ssv, n);
        k_fused<1><<<grid, 256, 0, stream>>>(x, afb, wt_b, y, bins, ssv);
    }
}

// Round 8
// 422.176 us; speedup vs baseline: 1.2323x; 1.1516x over previous
//
#include <hip/hip_runtime.h>
#include <math.h>

#define C_IN   64
#define T_DIM  256
#define V_DIM  25
#define C_OUT  256
#define S_DIM  3
#define BN_EPS 1e-5f

#define SC       (S_DIM * C_IN)          // 192
#define TW       (T_DIM * V_DIM)         // 6400
#define AP_PER_N (S_DIM * V_DIM * V_DIM) // 1875
#define LDB      200                     // sXa row stride in bf16 (400 B)
#define LDX      32                      // sX row stride in bf16 (64 B)
#define NR       32                      // atomic replica count

#define NBINS    (NR * 2 * C_OUT)        // 16384
#define NAP      (64 * AP_PER_N)         // 120000 (n=64)
#define NAFB     (64 * 6 * 64 * 8)       // 196608
#define NWT      (C_OUT * SC)            // 49152
#define PREP_TOT (NBINS + NAP + NAFB + NWT)
#define NY       ((size_t)64 * C_OUT * TW)   // 104857600

typedef __attribute__((ext_vector_type(8))) short bf16x8;
typedef __attribute__((ext_vector_type(4))) float f32x4;

__device__ __forceinline__ unsigned short f2bf(float f) {
    unsigned u = __builtin_bit_cast(unsigned, f);
    unsigned r = u + 0x7fffu + ((u >> 16) & 1u);
    return (unsigned short)(r >> 16);
}

// ---------------------------------------------------------------------------
// Merged prep: zero bins | out_ap=tanh | afb pack | wt_b pack — one launch.
// ---------------------------------------------------------------------------
__global__ void k_prep(const float* __restrict__ A, const float* __restrict__ A_pers,
                       const float* __restrict__ conv_w,
                       float* __restrict__ bins, float* __restrict__ out_ap,
                       unsigned short* __restrict__ afb, unsigned short* __restrict__ wt_b) {
    int i = blockIdx.x * 256 + threadIdx.x;
    if (i < NBINS) {
        bins[i] = 0.f;
        return;
    }
    i -= NBINS;
    if (i < NAP) {
        out_ap[i] = tanhf(A_pers[i]);
        return;
    }
    i -= NAP;
    if (i < NAFB) {
        int j    = i;
        int k    = j & 7;
        int lane = (j >> 3) & 63;
        int nt   = (j >> 9) & 1;
        int sn   = j >> 10;
        int s    = sn % 3;
        int n    = sn / 3;
        int v    = ((lane >> 4) << 3) + k;
        int w    = nt * 16 + (lane & 15);
        float val = 0.f;
        if (v < V_DIM && w < V_DIM)
            val = A[(s * V_DIM + v) * V_DIM + w] +
                  tanhf(A_pers[((n * S_DIM + s) * V_DIM + v) * V_DIM + w]);
        afb[j] = f2bf(val);
        return;
    }
    i -= NAFB;
    if (i < NWT) {
        int o  = i / SC;
        int sc = i - o * SC;
        int s  = sc >> 6, c = sc & 63;
        wt_b[i] = f2bf(conv_w[(s * C_OUT + o) * C_IN + c]);
    }
}

// ---------------------------------------------------------------------------
// k_pass0: block = (t-pair, n, z = o-half). Stage1 MFMA -> sXa (full xa tile);
// stage2 with REGISTER-RESIDENT weights for this block's 128-o half.
// Epilogue: channel sums (shfl + replica atomics) and y_pre bf16 dump
// (natural [n][o][tw] layout so k_final streams linearly).
// ---------------------------------------------------------------------------
__global__ __launch_bounds__(256, 3) void k_pass0(const float* __restrict__ x,
                                                  const unsigned short* __restrict__ afb,
                                                  const unsigned short* __restrict__ wt_b,
                                                  unsigned short* __restrict__ ypre,
                                                  float* __restrict__ bins) {
    __shared__ __align__(16) unsigned short sX[128 * LDX];   // 8 KB
    __shared__ __align__(16) unsigned short sXa[64 * LDB];   // 25.6 KB (reused for yS)

    const int tid  = threadIdx.x;
    const int tp   = blockIdx.x;
    const int nIdx = blockIdx.y;
    const int z    = blockIdx.z;       // o-half: 0 -> o<128, 1 -> o>=128
    const int lane = tid & 63;
    const int wv   = tid >> 6;
    const int l15  = lane & 15;
    const int kg   = lane >> 4;

    // ---- register-resident stage-2 weights for this wave's 32-o strip ----
    bf16x8 aF[2][6];
    {
        const unsigned short* wrow = wt_b + (size_t)(z * 128 + wv * 32 + l15) * SC + kg * 8;
#pragma unroll
        for (int m = 0; m < 2; ++m)
#pragma unroll
            for (int ks = 0; ks < 6; ++ks)
                aF[m][ks] = *(const bf16x8*)(wrow + m * 16 * SC + ks * 32);
    }
    // ---- stage-1 B-frags ----
    bf16x8 bS[6];
    {
        const unsigned short* afbN = afb + (size_t)nIdx * (6 * 64 * 8);
#pragma unroll
        for (int sq = 0; sq < 6; ++sq)
            bS[sq] = *(const bf16x8*)(afbN + (sq * 64 + lane) * 8);
    }

    // zero sX K-pad cols (v=25..31) and sXa pad rows (tw=50..63)
    for (int j = tid; j < 128 * 4; j += 256) {
        int row = j >> 2, p = j & 3;
        if (p == 0) sX[row * LDX + 25] = 0;
        else ((unsigned*)sX)[row * (LDX / 2) + 12 + p] = 0;
    }
    for (int j = tid; j < 14 * (LDB / 2); j += 256)
        ((unsigned*)sXa)[50 * (LDB / 2) + j] = 0;

    // stage x -> sX bf16 (float2-vectorized)
    {
        const float* xb = x + (size_t)nIdx * C_IN * TW + (size_t)tp * 2 * V_DIM;
        for (int q = tid; q < 1600; q += 256) {
            int c = q / 25, j = q - c * 25;
            float2 v2 = *(const float2*)(xb + (size_t)c * TW + 2 * j);
            unsigned short b0 = f2bf(v2.x), b1 = f2bf(v2.y);
            if (j < 12) {
                ((unsigned*)sX)[c * LDX + j] = (unsigned)b0 | ((unsigned)b1 << 16);
            } else if (j == 12) {
                sX[(2 * c) * LDX + 24] = b0;
                sX[(2 * c + 1) * LDX]  = b1;
            } else {
                int v = 2 * j - 25;
                sX[(2 * c + 1) * LDX + v]     = b0;
                sX[(2 * c + 1) * LDX + v + 1] = b1;
            }
        }
    }
    __syncthreads();

    // ---- stage 1: full xa tile, 12 MFMA/wave; paired-bf16 b32 LDS writes ----
#pragma unroll
    for (int sq = 0; sq < 6; ++sq) {
        int s = sq >> 1, nt = sq & 1;
        int w = nt * 16 + l15;
#pragma unroll
        for (int m2 = 0; m2 < 2; ++m2) {
            int mt = wv * 2 + m2;
            bf16x8 aX = *(const bf16x8*)(sX + (mt * 16 + l15) * LDX + kg * 8);
            f32x4 c4 = __builtin_amdgcn_mfma_f32_16x16x32_bf16(
                aX, bS[sq], (f32x4){0.f, 0.f, 0.f, 0.f}, 0, 0, 0);
            if (w < V_DIM) {
                unsigned u0 = (unsigned)f2bf(c4[0]) | ((unsigned)f2bf(c4[2]) << 16); // t=0
                unsigned u1 = (unsigned)f2bf(c4[1]) | ((unsigned)f2bf(c4[3]) << 16); // t=1
                unsigned col = s * 32 + mt * 4 + kg;
                ((unsigned*)sXa)[w * (LDB / 2) + col]           = u0;
                ((unsigned*)sXa)[(V_DIM + w) * (LDB / 2) + col] = u1;
            }
        }
    }
    __syncthreads();

    // ---- stage 2: M=32 per wave (2 m-frags), N=64, K=192; weights in regs ----
    f32x4 acc[2][4];
#pragma unroll
    for (int m = 0; m < 2; ++m)
#pragma unroll
        for (int nn = 0; nn < 4; ++nn) acc[m][nn] = (f32x4){0.f, 0.f, 0.f, 0.f};
#pragma unroll
    for (int ks = 0; ks < 6; ++ks) {
        bf16x8 bF[4];
#pragma unroll
        for (int nn = 0; nn < 4; ++nn)
            bF[nn] = *(const bf16x8*)(sXa + (nn * 16 + l15) * LDB + ks * 32 + kg * 8);
#pragma unroll
        for (int m = 0; m < 2; ++m)
#pragma unroll
            for (int nn = 0; nn < 4; ++nn)
                acc[m][nn] = __builtin_amdgcn_mfma_f32_16x16x32_bf16(aF[m][ks], bF[nn], acc[m][nn], 0, 0, 0);
    }

    // ---- channel sums (f32, pre-rounding) ----
    const int obase = z * 128 + wv * 32;
    {
        const int rep = (blockIdx.y * gridDim.x + blockIdx.x) & (NR - 1);
        float* b0 = bins + rep * 2 * C_OUT;
#pragma unroll
        for (int m = 0; m < 2; ++m) {
#pragma unroll
            for (int r = 0; r < 4; ++r) {
                float v0 = acc[m][0][r], v1 = acc[m][1][r], v2 = acc[m][2][r];
                float s1 = v0 + v1 + v2;
                float s2 = v0 * v0 + v1 * v1 + v2 * v2;
                if (l15 < 2) {                   // tw = 48+l15 < 50
                    float v3 = acc[m][3][r];
                    s1 += v3;
                    s2 += v3 * v3;
                }
#pragma unroll
                for (int off = 1; off < 16; off <<= 1) {
                    s1 += __shfl_xor(s1, off, 64);
                    s2 += __shfl_xor(s2, off, 64);
                }
                if (l15 == 0) {
                    int o = obase + m * 16 + kg * 4 + r;
                    atomicAdd(&b0[o], s1);
                    atomicAdd(&b0[C_OUT + o], s2);
                }
            }
        }
    }

    // ---- y_pre bf16 via LDS (reuse sXa): yS[o_local(128)][tw(50)] ----
    __syncthreads();                     // all sXa reads done
    unsigned short* yS = sXa;
#pragma unroll
    for (int m = 0; m < 2; ++m) {
#pragma unroll
        for (int r = 0; r < 4; ++r) {
            int ol = wv * 32 + m * 16 + kg * 4 + r;
            unsigned short* sp = yS + ol * 50 + l15;
            sp[0]  = f2bf(acc[m][0][r]);
            sp[16] = f2bf(acc[m][1][r]);
            sp[32] = f2bf(acc[m][2][r]);
            if (l15 < 2)
                sp[48] = f2bf(acc[m][3][r]);
        }
    }
    __syncthreads();

    // dump: 3200 u32, LDS-linear; global rows of 100 B per o
    {
        unsigned* ypu = (unsigned*)ypre;
        const size_t obg = (size_t)nIdx * C_OUT + z * 128;
        for (int q = tid; q < 3200; q += 256) {
            int ol = q / 25, jj = q - ol * 25;
            ypu[(obg + ol) * (TW / 2) + (size_t)tp * 25 + jj] = ((unsigned*)yS)[q];
        }
    }
}

// ---------------------------------------------------------------------------
__global__ void k_stats(const float* __restrict__ bins, const float* __restrict__ bn_w,
                        const float* __restrict__ bn_b, float2* __restrict__ ssv, int n) {
    int o = threadIdx.x;
    float s1 = 0.f, s2 = 0.f;
    for (int rp = 0; rp < NR; ++rp) {
        s1 += bins[rp * 2 * C_OUT + o];
        s2 += bins[rp * 2 * C_OUT + C_OUT + o];
    }
    float cnt   = (float)n * (float)TW;
    float mean  = s1 / cnt;
    float var   = s2 / cnt - mean * mean;
    float scale = bn_w[o] * rsqrtf(var + BN_EPS);
    ssv[o] = make_float2(scale, bn_b[o] - mean * scale);
}

// ---------------------------------------------------------------------------
// k_final: pure linear stream: read y_pre bf16 (16 B/lane), BN+ReLU,
// write y f32 (32 B/lane). ypre layout == y layout -> fully coalesced.
// ---------------------------------------------------------------------------
__global__ __launch_bounds__(256) void k_final(const unsigned short* __restrict__ ypre,
                                               const float2* __restrict__ ssv,
                                               float* __restrict__ y, unsigned total8) {
    unsigned stride = gridDim.x * 256u;
    for (unsigned i = blockIdx.x * 256u + threadIdx.x; i < total8; i += stride) {
        uint4 v = ((const uint4*)ypre)[i];
        unsigned o = (i / 800u) & 255u;      // 800 octets per (n,o) row
        float2 sh = ssv[o];
        float4 o0, o1;
        o0.x = fmaxf(fmaf(__builtin_bit_cast(float, v.x << 16),          sh.x, sh.y), 0.f);
        o0.y = fmaxf(fmaf(__builtin_bit_cast(float, v.x & 0xffff0000u),  sh.x, sh.y), 0.f);
        o0.z = fmaxf(fmaf(__builtin_bit_cast(float, v.y << 16),          sh.x, sh.y), 0.f);
        o0.w = fmaxf(fmaf(__builtin_bit_cast(float, v.y & 0xffff0000u),  sh.x, sh.y), 0.f);
        o1.x = fmaxf(fmaf(__builtin_bit_cast(float, v.z << 16),          sh.x, sh.y), 0.f);
        o1.y = fmaxf(fmaf(__builtin_bit_cast(float, v.z & 0xffff0000u),  sh.x, sh.y), 0.f);
        o1.z = fmaxf(fmaf(__builtin_bit_cast(float, v.w << 16),          sh.x, sh.y), 0.f);
        o1.w = fmaxf(fmaf(__builtin_bit_cast(float, v.w & 0xffff0000u),  sh.x, sh.y), 0.f);
        ((float4*)y)[2 * i]     = o0;
        ((float4*)y)[2 * i + 1] = o1;
    }
}

// ---------------------------------------------------------------------------
// Fallback fused kernel (R4, known-good) for small ws_size
// ---------------------------------------------------------------------------
template <int PASS>
__global__ __launch_bounds__(256, 4) void k_fused(const float* __restrict__ x,
                                                  const unsigned short* __restrict__ afb,
                                                  const unsigned short* __restrict__ wt_b,
                                                  float* __restrict__ y,
                                                  float* __restrict__ bins,
                                                  const float2* __restrict__ ssv) {
    __shared__ __align__(16) unsigned short sX[128 * LDX];
    __shared__ __align__(16) unsigned short sXa[64 * LDB];

    const int tid  = threadIdx.x;
    const int nIdx = blockIdx.y;
    const int t0   = blockIdx.x * 2;
    const int lane = tid & 63;
    const int wv   = tid >> 6;
    const int l15  = lane & 15;
    const int kg   = lane >> 4;

    bf16x8 bS[6];
    {
        const unsigned short* afbN = afb + (size_t)nIdx * (6 * 64 * 8);
#pragma unroll
        for (int sq = 0; sq < 6; ++sq)
            bS[sq] = *(const bf16x8*)(afbN + (sq * 64 + lane) * 8);
    }
    for (int j = tid; j < 128 * 4; j += 256) {
        int row = j >> 2, p = j & 3;
        if (p == 0) sX[row * LDX + 25] = 0;
        else ((unsigned*)sX)[row * (LDX / 2) + 12 + p] = 0;
    }
    {
        const float* xb = x + (size_t)nIdx * C_IN * TW + (size_t)t0 * V_DIM;
        for (int q = tid; q < 1600; q += 256) {
            int c = q / 25, j = q - c * 25;
            float2 v2 = *(const float2*)(xb + (size_t)c * TW + 2 * j);
            unsigned short b0 = f2bf(v2.x), b1 = f2bf(v2.y);
            if (j < 12) {
                ((unsigned*)sX)[c * LDX + j] = (unsigned)b0 | ((unsigned)b1 << 16);
            } else if (j == 12) {
                sX[(2 * c) * LDX + 24] = b0;
                sX[(2 * c + 1) * LDX]  = b1;
            } else {
                int v = 2 * j - 25;
                sX[(2 * c + 1) * LDX + v]     = b0;
                sX[(2 * c + 1) * LDX + v + 1] = b1;
            }
        }
    }
    __syncthreads();
#pragma unroll
    for (int sq = 0; sq < 6; ++sq) {
        int s = sq >> 1, nt = sq & 1;
        int w = nt * 16 + l15;
#pragma unroll
        for (int m2 = 0; m2 < 2; ++m2) {
            int mt = wv * 2 + m2;
            bf16x8 aX = *(const bf16x8*)(sX + (mt * 16 + l15) * LDX + kg * 8);
            f32x4 c4 = __builtin_amdgcn_mfma_f32_16x16x32_bf16(
                aX, bS[sq], (f32x4){0.f, 0.f, 0.f, 0.f}, 0, 0, 0);
            if (w < V_DIM) {
                unsigned u0 = (unsigned)f2bf(c4[0]) | ((unsigned)f2bf(c4[2]) << 16);
                unsigned u1 = (unsigned)f2bf(c4[1]) | ((unsigned)f2bf(c4[3]) << 16);
                unsigned col = s * 32 + mt * 4 + kg;
                ((unsigned*)sXa)[w * (LDB / 2) + col]           = u0;
                ((unsigned*)sXa)[(V_DIM + w) * (LDB / 2) + col] = u1;
            }
        }
    }
    __syncthreads();

    f32x4 acc[4][4];
#pragma unroll
    for (int m = 0; m < 4; ++m)
#pragma unroll
        for (int nn = 0; nn < 4; ++nn) acc[m][nn] = (f32x4){0.f, 0.f, 0.f, 0.f};

    const unsigned short* wrow = wt_b + (size_t)(wv * 64 + l15) * SC + kg * 8;
#pragma unroll
    for (int ks = 0; ks < 6; ++ks) {
        bf16x8 aF[4], bF[4];
#pragma unroll
        for (int m = 0; m < 4; ++m)
            aF[m] = *(const bf16x8*)(wrow + m * 16 * SC + ks * 32);
#pragma unroll
        for (int nn = 0; nn < 4; ++nn)
            bF[nn] = *(const bf16x8*)(sXa + (nn * 16 + l15) * LDB + ks * 32 + kg * 8);
#pragma unroll
        for (int m = 0; m < 4; ++m)
#pragma unroll
            for (int nn = 0; nn < 4; ++nn)
                acc[m][nn] = __builtin_amdgcn_mfma_f32_16x16x32_bf16(aF[m], bF[nn], acc[m][nn], 0, 0, 0);
    }

    const int wbase = wv * 64;
    if (PASS == 0) {
        const int rep = (blockIdx.y * gridDim.x + blockIdx.x) & (NR - 1);
        float* b0 = bins + rep * 2 * C_OUT;
#pragma unroll
        for (int m = 0; m < 4; ++m) {
#pragma unroll
            for (int r = 0; r < 4; ++r) {
                float v0 = acc[m][0][r], v1 = acc[m][1][r], v2 = acc[m][2][r];
                float s1 = v0 + v1 + v2;
                float s2 = v0 * v0 + v1 * v1 + v2 * v2;
                if (l15 < 2) {
                    float v3 = acc[m][3][r];
                    s1 += v3;
                    s2 += v3 * v3;
                }
#pragma unroll
                for (int off = 1; off < 16; off <<= 1) {
                    s1 += __shfl_xor(s1, off, 64);
                    s2 += __shfl_xor(s2, off, 64);
                }
                if (l15 == 0) {
                    int o = wbase + m * 16 + kg * 4 + r;
                    atomicAdd(&b0[o], s1);
                    atomicAdd(&b0[C_OUT + o], s2);
                }
            }
        }
    } else {
        const size_t ybase = (size_t)nIdx * C_OUT * TW + (size_t)t0 * V_DIM;
#pragma unroll
        for (int m = 0; m < 4; ++m) {
#pragma unroll
            for (int r = 0; r < 4; ++r) {
                int o = wbase + m * 16 + kg * 4 + r;
                float2 sh = ssv[o];
                float* yp = y + ybase + (size_t)o * TW + l15;
                yp[0]  = fmaxf(fmaf(acc[m][0][r], sh.x, sh.y), 0.f);
                yp[16] = fmaxf(fmaf(acc[m][1][r], sh.x, sh.y), 0.f);
                yp[32] = fmaxf(fmaf(acc[m][2][r], sh.x, sh.y), 0.f);
                if (l15 < 2)
                    yp[48] = fmaxf(fmaf(acc[m][3][r], sh.x, sh.y), 0.f);
            }
        }
    }
}

// ---------------------------------------------------------------------------
extern "C" void kernel_launch(void* const* d_in, const int* in_sizes, int n_in,
                              void* d_out, int out_size, void* d_ws, size_t ws_size,
                              hipStream_t stream) {
    const float* x      = (const float*)d_in[0];
    const float* A      = (const float*)d_in[1];
    const float* A_pers = (const float*)d_in[2];
    const float* conv_w = (const float*)d_in[3];
    // d_in[4] = conv_b: cancels under training-mode BatchNorm -> unused
    const float* bn_w   = (const float*)d_in[5];
    const float* bn_b   = (const float*)d_in[6];

    const int n = in_sizes[0] / (C_IN * TW);   // 64

    float* out_ap = (float*)d_out;
    float* y      = (float*)d_out + (size_t)n * AP_PER_N;

    // ws layout
    float*  bins = (float*)d_ws;                                    // 64 KB
    float2* ssv  = (float2*)(bins + NBINS);                         // 2 KB
    unsigned short* afb  = (unsigned short*)((char*)(ssv + C_OUT)); // 384 KB
    unsigned short* wt_b = afb + (size_t)NAFB;                      // 96 KB
    unsigned short* ypre = wt_b + (size_t)NWT;                      // 209.7 MB (16B-aligned: 559104 % 16 == 0)
    const size_t need = (size_t)NBINS * 4 + C_OUT * 8 +
                        ((size_t)NAFB + NWT + NY) * 2;

    // one merged prep launch: zero bins + out_ap + afb + wt_b
    k_prep<<<(PREP_TOT + 255) / 256, 256, 0, stream>>>(A, A_pers, conv_w,
                                                       bins, out_ap, afb, wt_b);

    if (ws_size >= need) {
        k_pass0<<<dim3(T_DIM / 2, n, 2), 256, 0, stream>>>(x, afb, wt_b, ypre, bins);
        k_stats<<<1, 256, 0, stream>>>(bins, bn_w, bn_b, ssv, n);
        k_final<<<2048, 256, 0, stream>>>(ypre, ssv, y, (unsigned)(NY / 8));
    } else {
        dim3 grid(T_DIM / 2, n);
        k_fused<0><<<grid, 256, 0, stream>>>(x, afb, wt_b, y, bins, ssv);
        k_stats<<<1, 256, 0, stream>>>(bins, bn_w, bn_b, ssv, n);
        k_fused<1><<<grid, 256, 0, stream>>>(x, afb, wt_b, y, bins, ssv);
    }
}

// Round 10
// 349.044 us; speedup vs baseline: 1.4906x; 1.2095x over previous
//
#include <hip/hip_runtime.h>
#include <math.h>

#define C_IN   64
#define T_DIM  256
#define V_DIM  25
#define C_OUT  256
#define S_DIM  3
#define BN_EPS 1e-5f

#define SC       (S_DIM * C_IN)          // 192
#define TW       (T_DIM * V_DIM)         // 6400
#define AP_PER_N (S_DIM * V_DIM * V_DIM) // 1875
#define LDB      200                     // sXa row stride in bf16 (400 B)
#define NR       32                      // atomic replica count

#define NBINS    (NR * 2 * C_OUT)        // 16384
#define NAP      (64 * AP_PER_N)         // 120000 (n=64)
#define NAFB     (64 * 6 * 64 * 8)       // 196608
#define NWT      (C_OUT * SC)            // 49152
#define PREP_TOT (NBINS + NAP + NAFB + NWT)
#define NXU      (64 * 128 * 128 * 16)   // x_re uints (2 bf16 each) = 16.78M

typedef __attribute__((ext_vector_type(8))) short bf16x8;
typedef __attribute__((ext_vector_type(4))) float f32x4;

__device__ __forceinline__ unsigned short f2bf(float f) {
    unsigned u = __builtin_bit_cast(unsigned, f);
    unsigned r = u + 0x7fffu + ((u >> 16) & 1u);
    return (unsigned short)(r >> 16);
}

// ---------------------------------------------------------------------------
// Merged prep: zero bins | out_ap=tanh | afb pack | wt_b pack — one launch.
// ---------------------------------------------------------------------------
__global__ void k_prep(const float* __restrict__ A, const float* __restrict__ A_pers,
                       const float* __restrict__ conv_w,
                       float* __restrict__ bins, float* __restrict__ out_ap,
                       unsigned short* __restrict__ afb, unsigned short* __restrict__ wt_b) {
    int i = blockIdx.x * 256 + threadIdx.x;
    if (i < NBINS) {
        bins[i] = 0.f;
        return;
    }
    i -= NBINS;
    if (i < NAP) {
        out_ap[i] = tanhf(A_pers[i]);
        return;
    }
    i -= NAP;
    if (i < NAFB) {
        int j    = i;
        int k    = j & 7;
        int lane = (j >> 3) & 63;
        int nt   = (j >> 9) & 1;
        int sn   = j >> 10;
        int s    = sn % 3;
        int n    = sn / 3;
        int v    = ((lane >> 4) << 3) + k;
        int w    = nt * 16 + (lane & 15);
        float val = 0.f;
        if (v < V_DIM && w < V_DIM)
            val = A[(s * V_DIM + v) * V_DIM + w] +
                  tanhf(A_pers[((n * S_DIM + s) * V_DIM + v) * V_DIM + w]);
        afb[j] = f2bf(val);
        return;
    }
    i -= NAFB;
    if (i < NWT) {
        int o  = i / SC;
        int sc = i - o * SC;
        int s  = sc >> 6, c = sc & 63;
        wt_b[i] = f2bf(conv_w[(s * C_OUT + o) * C_IN + c]);
    }
}

// ---------------------------------------------------------------------------
// k_prepx: one-time x relayout -> bf16 tiles x_re[tile=n*128+tp][row=2c+t][32]
// (cols 25..31 zero-padded).  Thread writes one uint (2 bf16).
// ---------------------------------------------------------------------------
__global__ __launch_bounds__(256) void k_prepx(const float* __restrict__ x,
                                               unsigned* __restrict__ x_re) {
    int j = blockIdx.x * 256 + threadIdx.x;
    if (j >= NXU) return;
    int tile = j >> 11;          // 2048 uints per tile
    int rem  = j & 2047;
    int row  = rem >> 4;         // 0..127 = 2c+t
    int vp   = rem & 15;         // uint col (v pair)
    int n = tile >> 7, tp = tile & 127;
    int c = row >> 1, t = row & 1;
    const float* src = x + (size_t)n * (C_IN * TW) + (size_t)c * TW + (2 * tp + t) * V_DIM;
    int v0 = vp * 2;
    unsigned lo = (v0 < V_DIM)     ? f2bf(src[v0])     : 0;
    unsigned hi = (v0 + 1 < V_DIM) ? f2bf(src[v0 + 1]) : 0;
    x_re[j] = lo | (hi << 16);
}

// ---------------------------------------------------------------------------
// k_gemm<PASS>: block = (t-pair, n, z = o-half).
// Stage1: aX regs (direct global), MFMA -> sXa bf16 [tw][sc].
// Stage2: MFMA, register-resident weights (this block's 128-o half).
// PASS 0: channel sum/sumsq -> shfl-reduce + replica atomics.
// PASS 1: BN+ReLU, f32 LDS transpose (yS aliases sXa) -> 200B-run y writes.
// ---------------------------------------------------------------------------
template <int PASS>
__global__ __launch_bounds__(256, 3) void k_gemm(const unsigned short* __restrict__ x_re,
                                                 const unsigned short* __restrict__ afb,
                                                 const unsigned short* __restrict__ wt_b,
                                                 float* __restrict__ y,
                                                 float* __restrict__ bins,
                                                 const float2* __restrict__ ssv) {
    __shared__ __align__(16) unsigned short sXa[64 * LDB];   // 25.6 KB; pass1: reused as yS f32[128][50]

    const int tid  = threadIdx.x;
    const int tp   = blockIdx.x;
    const int nIdx = blockIdx.y;
    const int z    = blockIdx.z;       // o-half
    const int lane = tid & 63;
    const int wv   = tid >> 6;
    const int l15  = lane & 15;
    const int kg   = lane >> 4;

    // ---- register-resident stage-2 weights (wave's 32-o strip) ----
    bf16x8 aF[2][6];
    {
        const unsigned short* wrow = wt_b + (size_t)(z * 128 + wv * 32 + l15) * SC + kg * 8;
#pragma unroll
        for (int m = 0; m < 2; ++m)
#pragma unroll
            for (int ks = 0; ks < 6; ++ks)
                aF[m][ks] = *(const bf16x8*)(wrow + m * 16 * SC + ks * 32);
    }
    // ---- stage-1 B-frags (Af) ----
    bf16x8 bS[6];
    {
        const unsigned short* afbN = afb + (size_t)nIdx * (6 * 64 * 8);
#pragma unroll
        for (int sq = 0; sq < 6; ++sq)
            bS[sq] = *(const bf16x8*)(afbN + (sq * 64 + lane) * 8);
    }
    // ---- stage-1 A-frags: direct from relayed x (1KB contiguous per mt) ----
    bf16x8 aX[2];
    {
        const unsigned short* xt = x_re + (size_t)(nIdx * 128 + tp) * 4096;
#pragma unroll
        for (int m2 = 0; m2 < 2; ++m2)
            aX[m2] = *(const bf16x8*)(xt + ((wv * 2 + m2) * 16 + l15) * 32 + kg * 8);
    }

    // zero sXa pad rows (tw = 50..63)
    for (int j = tid; j < 14 * (LDB / 2); j += 256)
        ((unsigned*)sXa)[50 * (LDB / 2) + j] = 0;

    // ---- stage 1: 12 MFMA/wave; paired-bf16 b32 LDS writes ----
#pragma unroll
    for (int sq = 0; sq < 6; ++sq) {
        int s = sq >> 1, nt = sq & 1;
        int w = nt * 16 + l15;
#pragma unroll
        for (int m2 = 0; m2 < 2; ++m2) {
            int mt = wv * 2 + m2;
            f32x4 c4 = __builtin_amdgcn_mfma_f32_16x16x32_bf16(
                aX[m2], bS[sq], (f32x4){0.f, 0.f, 0.f, 0.f}, 0, 0, 0);
            if (w < V_DIM) {
                unsigned u0 = (unsigned)f2bf(c4[0]) | ((unsigned)f2bf(c4[2]) << 16); // t=0
                unsigned u1 = (unsigned)f2bf(c4[1]) | ((unsigned)f2bf(c4[3]) << 16); // t=1
                unsigned col = s * 32 + mt * 4 + kg;
                ((unsigned*)sXa)[w * (LDB / 2) + col]           = u0;
                ((unsigned*)sXa)[(V_DIM + w) * (LDB / 2) + col] = u1;
            }
        }
    }
    __syncthreads();

    // ---- stage 2: M=32/wave (2 m-frags), N=64 (50 valid), K=192 ----
    f32x4 acc[2][4];
#pragma unroll
    for (int m = 0; m < 2; ++m)
#pragma unroll
        for (int nn = 0; nn < 4; ++nn) acc[m][nn] = (f32x4){0.f, 0.f, 0.f, 0.f};
#pragma unroll
    for (int ks = 0; ks < 6; ++ks) {
        bf16x8 bF[4];
#pragma unroll
        for (int nn = 0; nn < 4; ++nn)
            bF[nn] = *(const bf16x8*)(sXa + (nn * 16 + l15) * LDB + ks * 32 + kg * 8);
#pragma unroll
        for (int m = 0; m < 2; ++m)
#pragma unroll
            for (int nn = 0; nn < 4; ++nn)
                acc[m][nn] = __builtin_amdgcn_mfma_f32_16x16x32_bf16(aF[m][ks], bF[nn], acc[m][nn], 0, 0, 0);
    }

    const int obase = z * 128 + wv * 32;
    if (PASS == 0) {
        // ---- channel sums -> shfl-reduce over l15, replica atomics ----
        const int rep = (blockIdx.y * gridDim.x + blockIdx.x) & (NR - 1);
        float* b0 = bins + rep * 2 * C_OUT;
#pragma unroll
        for (int m = 0; m < 2; ++m) {
#pragma unroll
            for (int r = 0; r < 4; ++r) {
                float v0 = acc[m][0][r], v1 = acc[m][1][r], v2 = acc[m][2][r];
                float s1 = v0 + v1 + v2;
                float s2 = v0 * v0 + v1 * v1 + v2 * v2;
                if (l15 < 2) {                   // tw = 48+l15 < 50
                    float v3 = acc[m][3][r];
                    s1 += v3;
                    s2 += v3 * v3;
                }
#pragma unroll
                for (int off = 1; off < 16; off <<= 1) {
                    s1 += __shfl_xor(s1, off, 64);
                    s2 += __shfl_xor(s2, off, 64);
                }
                if (l15 == 0) {
                    int o = obase + m * 16 + kg * 4 + r;
                    atomicAdd(&b0[o], s1);
                    atomicAdd(&b0[C_OUT + o], s2);
                }
            }
        }
    } else {
        // ---- BN+ReLU; transpose via yS (aliases sXa); 200B-run y writes ----
        float2 sh[2][4];
#pragma unroll
        for (int m = 0; m < 2; ++m)
#pragma unroll
            for (int r = 0; r < 4; ++r)
                sh[m][r] = ssv[obase + m * 16 + kg * 4 + r];

        __syncthreads();                 // all sXa reads done before overwrite
        float* yS = (float*)sXa;         // [128 o_local][50 tw] = 25.6 KB exact
#pragma unroll
        for (int m = 0; m < 2; ++m) {
#pragma unroll
            for (int r = 0; r < 4; ++r) {
                int ol = wv * 32 + m * 16 + kg * 4 + r;
                float sc = sh[m][r].x, sf = sh[m][r].y;
                float* sp = yS + ol * 50 + l15;
                sp[0]  = fmaxf(fmaf(acc[m][0][r], sc, sf), 0.f);
                sp[16] = fmaxf(fmaf(acc[m][1][r], sc, sf), 0.f);
                sp[32] = fmaxf(fmaf(acc[m][2][r], sc, sf), 0.f);
                if (l15 < 2)
                    sp[48] = fmaxf(fmaf(acc[m][3][r], sc, sf), 0.f);
            }
        }
        __syncthreads();

        // dump: 3200 float2; rows of 50 f32 = 200B contiguous per o
        float* ydst = y + ((size_t)nIdx * C_OUT + z * 128) * TW + (size_t)tp * 50;
        int o = tid / 25, j = tid - (tid / 25) * 25;
#pragma unroll
        for (int k = 0; k < 13; ++k) {
            int q = tid + k * 256;
            if (q < 3200) {
                float2 v = *(const float2*)(yS + o * 50 + 2 * j);
                *(float2*)(ydst + (size_t)o * TW + 2 * j) = v;
            }
            o += 10; j += 6;
            if (j >= 25) { j -= 25; ++o; }
        }
    }
}

// ---------------------------------------------------------------------------
__global__ void k_stats(const float* __restrict__ bins, const float* __restrict__ bn_w,
                        const float* __restrict__ bn_b, float2* __restrict__ ssv, int n) {
    int o = threadIdx.x;
    float s1 = 0.f, s2 = 0.f;
    for (int rp = 0; rp < NR; ++rp) {
        s1 += bins[rp * 2 * C_OUT + o];
        s2 += bins[rp * 2 * C_OUT + C_OUT + o];
    }
    float cnt   = (float)n * (float)TW;
    float mean  = s1 / cnt;
    float var   = s2 / cnt - mean * mean;
    float scale = bn_w[o] * rsqrtf(var + BN_EPS);
    ssv[o] = make_float2(scale, bn_b[o] - mean * scale);
}

// ---------------------------------------------------------------------------
extern "C" void kernel_launch(void* const* d_in, const int* in_sizes, int n_in,
                              void* d_out, int out_size, void* d_ws, size_t ws_size,
                              hipStream_t stream) {
    const float* x      = (const float*)d_in[0];
    const float* A      = (const float*)d_in[1];
    const float* A_pers = (const float*)d_in[2];
    const float* conv_w = (const float*)d_in[3];
    // d_in[4] = conv_b: cancels under training-mode BatchNorm -> unused
    const float* bn_w   = (const float*)d_in[5];
    const float* bn_b   = (const float*)d_in[6];

    const int n = in_sizes[0] / (C_IN * TW);   // 64

    float* out_ap = (float*)d_out;
    float* y      = (float*)d_out + (size_t)n * AP_PER_N;

    // ws layout (~67.7 MB total; harness provides >200 MB per R6 run)
    float*  bins = (float*)d_ws;                                    // 64 KB
    float2* ssv  = (float2*)(bins + NBINS);                         // 2 KB
    unsigned short* afb  = (unsigned short*)((char*)(ssv + C_OUT)); // 384 KB
    unsigned short* wt_b = afb + (size_t)NAFB;                      // 96 KB
    unsigned short* x_re = wt_b + (size_t)NWT;                      // 67.1 MB (offset 559104, 16B-aligned)

    // merged prep: zero bins + out_ap + afb + wt_b (one launch, no memset node)
    k_prep<<<(PREP_TOT + 255) / 256, 256, 0, stream>>>(A, A_pers, conv_w,
                                                       bins, out_ap, afb, wt_b);
    // one-time x relayout -> bf16 padded tiles
    k_prepx<<<NXU / 256, 256, 0, stream>>>(x, (unsigned*)x_re);

    dim3 grid(T_DIM / 2, n, 2);
    k_gemm<0><<<grid, 256, 0, stream>>>(x_re, afb, wt_b, y, bins, ssv);
    k_stats<<<1, 256, 0, stream>>>(bins, bn_w, bn_b, ssv, n);
    k_gemm<1><<<grid, 256, 0, stream>>>(x_re, afb, wt_b, y, bins, ssv);
}

// Round 11
// 330.039 us; speedup vs baseline: 1.5764x; 1.0576x over previous
//
#include <hip/hip_runtime.h>
#include <math.h>

#define C_IN   64
#define T_DIM  256
#define V_DIM  25
#define C_OUT  256
#define S_DIM  3
#define BN_EPS 1e-5f

#define SC       (S_DIM * C_IN)          // 192
#define TW       (T_DIM * V_DIM)         // 6400
#define AP_PER_N (S_DIM * V_DIM * V_DIM) // 1875
#define LDB      200                     // sXa row stride in bf16 (400 B)
#define NR       32                      // atomic replica count

#define NBINS    (NR * 2 * C_OUT)        // 16384
#define NAP      (64 * AP_PER_N)         // 120000 (n=64)
#define NAFB     (64 * 6 * 64 * 8)       // 196608
#define NWT      (C_OUT * SC)            // 49152
#define PREP_TOT (NBINS + NAP + NAFB + NWT)
#define NXU      (64 * 128 * 128 * 16)   // x_re uints (2 bf16 each)

typedef __attribute__((ext_vector_type(8))) short bf16x8;
typedef __attribute__((ext_vector_type(4))) float f32x4;

__device__ __forceinline__ unsigned short f2bf(float f) {
    unsigned u = __builtin_bit_cast(unsigned, f);
    unsigned r = u + 0x7fffu + ((u >> 16) & 1u);
    return (unsigned short)(r >> 16);
}

// Native scalar cast -> compiler emits v_cvt_pk_bf16_f32 for pairs (no asm).
__device__ __forceinline__ unsigned pk_bf16(float a, float b) {
    unsigned short ul = __builtin_bit_cast(unsigned short, (__bf16)a);
    unsigned short uh = __builtin_bit_cast(unsigned short, (__bf16)b);
    return (unsigned)ul | ((unsigned)uh << 16);
}

// ---------------------------------------------------------------------------
// Merged prep: zero bins | out_ap=tanh | afb pack | wt_b pack — one launch.
// ---------------------------------------------------------------------------
__global__ void k_prep(const float* __restrict__ A, const float* __restrict__ A_pers,
                       const float* __restrict__ conv_w,
                       float* __restrict__ bins, float* __restrict__ out_ap,
                       unsigned short* __restrict__ afb, unsigned short* __restrict__ wt_b) {
    int i = blockIdx.x * 256 + threadIdx.x;
    if (i < NBINS) {
        bins[i] = 0.f;
        return;
    }
    i -= NBINS;
    if (i < NAP) {
        out_ap[i] = tanhf(A_pers[i]);
        return;
    }
    i -= NAP;
    if (i < NAFB) {
        int j    = i;
        int k    = j & 7;
        int lane = (j >> 3) & 63;
        int nt   = (j >> 9) & 1;
        int sn   = j >> 10;
        int s    = sn % 3;
        int n    = sn / 3;
        int v    = ((lane >> 4) << 3) + k;
        int w    = nt * 16 + (lane & 15);
        float val = 0.f;
        if (v < V_DIM && w < V_DIM)
            val = A[(s * V_DIM + v) * V_DIM + w] +
                  tanhf(A_pers[((n * S_DIM + s) * V_DIM + v) * V_DIM + w]);
        afb[j] = f2bf(val);
        return;
    }
    i -= NAFB;
    if (i < NWT) {
        int o  = i / SC;
        int sc = i - o * SC;
        int s  = sc >> 6, c = sc & 63;
        wt_b[i] = f2bf(conv_w[(s * C_OUT + o) * C_IN + c]);
    }
}

// ---------------------------------------------------------------------------
// k_prepx: one-time x relayout -> bf16 tiles x_re[tile=n*128+tp][row=2c+t][32]
// (cols 25..31 zero-padded).  Thread writes one uint (2 bf16).
// ---------------------------------------------------------------------------
__global__ __launch_bounds__(256) void k_prepx(const float* __restrict__ x,
                                               unsigned* __restrict__ x_re) {
    int j = blockIdx.x * 256 + threadIdx.x;
    if (j >= NXU) return;
    int tile = j >> 11;          // 2048 uints per tile
    int rem  = j & 2047;
    int row  = rem >> 4;         // 0..127 = 2c+t
    int vp   = rem & 15;         // uint col (v pair)
    int n = tile >> 7, tp = tile & 127;
    int c = row >> 1, t = row & 1;
    const float* src = x + (size_t)n * (C_IN * TW) + (size_t)c * TW + (2 * tp + t) * V_DIM;
    int v0 = vp * 2;
    unsigned lo = (v0 < V_DIM)     ? f2bf(src[v0])     : 0;
    unsigned hi = (v0 + 1 < V_DIM) ? f2bf(src[v0 + 1]) : 0;
    x_re[j] = lo | (hi << 16);
}

// ---------------------------------------------------------------------------
// k_gemm<PASS>: block = (tp2 = 2 t-pairs, n, z = o-quarter of 64).
// Stage1: aX regs (direct global), MFMA -> sXa[u] bf16 [tw][sc], u = tile 0/1.
// Stage2: MFMA, register-resident 16-o weight strip per wave.
// PASS 0: channel sum/sumsq -> shfl-reduce + replica atomics.
// PASS 1: BN+ReLU, f32 LDS transpose (yS aliases sXa) -> 400B-run y writes.
// ---------------------------------------------------------------------------
template <int PASS>
__global__ __launch_bounds__(256, 3) void k_gemm(const unsigned short* __restrict__ x_re,
                                                 const unsigned short* __restrict__ afb,
                                                 const unsigned short* __restrict__ wt_b,
                                                 float* __restrict__ y,
                                                 float* __restrict__ bins,
                                                 const float2* __restrict__ ssv) {
    __shared__ __align__(16) unsigned short sXa[2][64 * LDB];  // 51.2 KB; pass1: aliased as yS f32[64][100]

    const int tid  = threadIdx.x;
    const int tp2  = blockIdx.x;       // covers t-pairs 2*tp2, 2*tp2+1
    const int nIdx = blockIdx.y;
    const int z    = blockIdx.z;       // o-quarter (64 channels)
    const int lane = tid & 63;
    const int wv   = tid >> 6;
    const int l15  = lane & 15;
    const int kg   = lane >> 4;

    // ---- register-resident stage-2 weights (wave's 16-o strip): 6 x b128 ----
    bf16x8 aF[6];
    {
        const unsigned short* wrow = wt_b + (size_t)(z * 64 + wv * 16 + l15) * SC + kg * 8;
#pragma unroll
        for (int ks = 0; ks < 6; ++ks)
            aF[ks] = *(const bf16x8*)(wrow + ks * 32);
    }
    // ---- stage-1 B-frags (Af) ----
    bf16x8 bS[6];
    {
        const unsigned short* afbN = afb + (size_t)nIdx * (6 * 64 * 8);
#pragma unroll
        for (int sq = 0; sq < 6; ++sq)
            bS[sq] = *(const bf16x8*)(afbN + (sq * 64 + lane) * 8);
    }
    // ---- stage-1 A-frags: direct from relayed x (1KB contiguous per mt) ----
    bf16x8 aX[2][2];
    {
        const unsigned short* xt0 = x_re + (size_t)(nIdx * 128 + tp2 * 2) * 4096;
#pragma unroll
        for (int u = 0; u < 2; ++u)
#pragma unroll
            for (int m2 = 0; m2 < 2; ++m2)
                aX[u][m2] = *(const bf16x8*)(xt0 + u * 4096 + ((wv * 2 + m2) * 16 + l15) * 32 + kg * 8);
    }

    // zero sXa pad rows (tw = 50..63) of both tiles: 2 x 1400 uints
    for (int j = tid; j < 2800; j += 256) {
        int u = j >= 1400, jj = j - u * 1400;
        ((unsigned*)sXa[u])[50 * (LDB / 2) + jj] = 0;
    }

    // ---- stage 1: 24 MFMA/wave; packed bf16 b32 LDS writes ----
#pragma unroll
    for (int sq = 0; sq < 6; ++sq) {
        int s = sq >> 1, nt = sq & 1;
        int w = nt * 16 + l15;
#pragma unroll
        for (int u = 0; u < 2; ++u) {
#pragma unroll
            for (int m2 = 0; m2 < 2; ++m2) {
                int mt = wv * 2 + m2;
                f32x4 c4 = __builtin_amdgcn_mfma_f32_16x16x32_bf16(
                    aX[u][m2], bS[sq], (f32x4){0.f, 0.f, 0.f, 0.f}, 0, 0, 0);
                if (w < V_DIM) {
                    unsigned u0 = pk_bf16(c4[0], c4[2]);   // t=0
                    unsigned u1 = pk_bf16(c4[1], c4[3]);   // t=1
                    unsigned col = s * 32 + mt * 4 + kg;
                    ((unsigned*)sXa[u])[w * (LDB / 2) + col]           = u0;
                    ((unsigned*)sXa[u])[(V_DIM + w) * (LDB / 2) + col] = u1;
                }
            }
        }
    }
    __syncthreads();

    // ---- stage 2: M=16/wave, N=2x64 (2x50 valid), K=192 ----
    f32x4 acc[2][4];
#pragma unroll
    for (int u = 0; u < 2; ++u)
#pragma unroll
        for (int nn = 0; nn < 4; ++nn) acc[u][nn] = (f32x4){0.f, 0.f, 0.f, 0.f};
#pragma unroll
    for (int ks = 0; ks < 6; ++ks) {
        bf16x8 bF[2][4];
#pragma unroll
        for (int u = 0; u < 2; ++u)
#pragma unroll
            for (int nn = 0; nn < 4; ++nn)
                bF[u][nn] = *(const bf16x8*)(sXa[u] + (nn * 16 + l15) * LDB + ks * 32 + kg * 8);
#pragma unroll
        for (int u = 0; u < 2; ++u)
#pragma unroll
            for (int nn = 0; nn < 4; ++nn)
                acc[u][nn] = __builtin_amdgcn_mfma_f32_16x16x32_bf16(aF[ks], bF[u][nn], acc[u][nn], 0, 0, 0);
    }

    const int obase = z * 64 + wv * 16;
    if (PASS == 0) {
        // ---- channel sums over both tiles -> shfl-reduce, replica atomics ----
        const int rep = (blockIdx.y * gridDim.x + blockIdx.x) & (NR - 1);
        float* b0 = bins + rep * 2 * C_OUT;
#pragma unroll
        for (int r = 0; r < 4; ++r) {
            float s1 = 0.f, s2 = 0.f;
#pragma unroll
            for (int u = 0; u < 2; ++u) {
                float v0 = acc[u][0][r], v1 = acc[u][1][r], v2 = acc[u][2][r];
                s1 += v0 + v1 + v2;
                s2 += v0 * v0 + v1 * v1 + v2 * v2;
                if (l15 < 2) {                   // tw = 48+l15 < 50
                    float v3 = acc[u][3][r];
                    s1 += v3;
                    s2 += v3 * v3;
                }
            }
#pragma unroll
            for (int off = 1; off < 16; off <<= 1) {
                s1 += __shfl_xor(s1, off, 64);
                s2 += __shfl_xor(s2, off, 64);
            }
            if (l15 == 0) {
                int o = obase + kg * 4 + r;
                atomicAdd(&b0[o], s1);
                atomicAdd(&b0[C_OUT + o], s2);
            }
        }
    } else {
        // ---- BN+ReLU; transpose via yS (aliases sXa); 400B-run y writes ----
        float2 sh[4];
#pragma unroll
        for (int r = 0; r < 4; ++r)
            sh[r] = ssv[obase + kg * 4 + r];

        __syncthreads();                 // all sXa reads done before overwrite
        float* yS = (float*)sXa;         // [64 o_local][100 tw] = 25.6 KB
#pragma unroll
        for (int r = 0; r < 4; ++r) {
            int ol = wv * 16 + kg * 4 + r;
            float sc = sh[r].x, sf = sh[r].y;
#pragma unroll
            for (int u = 0; u < 2; ++u) {
                float* sp = yS + ol * 100 + u * 50 + l15;
                sp[0]  = fmaxf(fmaf(acc[u][0][r], sc, sf), 0.f);
                sp[16] = fmaxf(fmaf(acc[u][1][r], sc, sf), 0.f);
                sp[32] = fmaxf(fmaf(acc[u][2][r], sc, sf), 0.f);
                if (l15 < 2)
                    sp[48] = fmaxf(fmaf(acc[u][3][r], sc, sf), 0.f);
            }
        }
        __syncthreads();

        // dump: 3200 float2; rows of 100 f32 = 400B contiguous per o
        float* ydst = y + ((size_t)nIdx * C_OUT + z * 64) * TW + (size_t)tp2 * 100;
#pragma unroll
        for (int k = 0; k < 13; ++k) {
            int q = tid + k * 256;
            if (q < 3200) {
                int o = q / 50, j2 = q - o * 50;
                float2 v = *(const float2*)(yS + o * 100 + 2 * j2);
                *(float2*)(ydst + (size_t)o * TW + 2 * j2) = v;
            }
        }
    }
}

// ---------------------------------------------------------------------------
__global__ void k_stats(const float* __restrict__ bins, const float* __restrict__ bn_w,
                        const float* __restrict__ bn_b, float2* __restrict__ ssv, int n) {
    int o = threadIdx.x;
    float s1 = 0.f, s2 = 0.f;
    for (int rp = 0; rp < NR; ++rp) {
        s1 += bins[rp * 2 * C_OUT + o];
        s2 += bins[rp * 2 * C_OUT + C_OUT + o];
    }
    float cnt   = (float)n * (float)TW;
    float mean  = s1 / cnt;
    float var   = s2 / cnt - mean * mean;
    float scale = bn_w[o] * rsqrtf(var + BN_EPS);
    ssv[o] = make_float2(scale, bn_b[o] - mean * scale);
}

// ---------------------------------------------------------------------------
extern "C" void kernel_launch(void* const* d_in, const int* in_sizes, int n_in,
                              void* d_out, int out_size, void* d_ws, size_t ws_size,
                              hipStream_t stream) {
    const float* x      = (const float*)d_in[0];
    const float* A      = (const float*)d_in[1];
    const float* A_pers = (const float*)d_in[2];
    const float* conv_w = (const float*)d_in[3];
    // d_in[4] = conv_b: cancels under training-mode BatchNorm -> unused
    const float* bn_w   = (const float*)d_in[5];
    const float* bn_b   = (const float*)d_in[6];

    const int n = in_sizes[0] / (C_IN * TW);   // 64

    float* out_ap = (float*)d_out;
    float* y      = (float*)d_out + (size_t)n * AP_PER_N;

    // ws layout (~67.7 MB total)
    float*  bins = (float*)d_ws;                                    // 64 KB
    float2* ssv  = (float2*)(bins + NBINS);                         // 2 KB
    unsigned short* afb  = (unsigned short*)((char*)(ssv + C_OUT)); // 384 KB
    unsigned short* wt_b = afb + (size_t)NAFB;                      // 96 KB
    unsigned short* x_re = wt_b + (size_t)NWT;                      // 67.1 MB

    // merged prep: zero bins + out_ap + afb + wt_b (one launch, no memset node)
    k_prep<<<(PREP_TOT + 255) / 256, 256, 0, stream>>>(A, A_pers, conv_w,
                                                       bins, out_ap, afb, wt_b);
    // one-time x relayout -> bf16 padded tiles
    k_prepx<<<NXU / 256, 256, 0, stream>>>(x, (unsigned*)x_re);

    dim3 grid(T_DIM / 4, n, 4);
    k_gemm<0><<<grid, 256, 0, stream>>>(x_re, afb, wt_b, y, bins, ssv);
    k_stats<<<1, 256, 0, stream>>>(bins, bn_w, bn_b, ssv, n);
    k_gemm<1><<<grid, 256, 0, stream>>>(x_re, afb, wt_b, y, bins, ssv);
}